// Round 5
// baseline (1735.355 us; speedup 1.0000x reference)
//
#include <hip/hip_runtime.h>
#include <hip/hip_bf16.h>

// ---------------------------------------------------------------------------
// Round 5: merged persistent kernel. Grid 256 x 1024thr, 8 sites/block.
// LDS ping-pong: region[p] = X(s) -> attn slots; region[1-p] <- x(s+1)
// streamed during proj(s) (issue-early / write-late, riding the GEMM loop).
// Attention in 2 rounds of 4 heads; q/k/vT compressed to bf16 regs between
// proj and their round. Direct full-line f32x4 out stores (no staging).
//   x:(2,1024,64,512) f32  w:(1536,512) f32  pb:(8,64,64) f32  mk:(2,) bool
// ---------------------------------------------------------------------------

typedef __attribute__((ext_vector_type(4))) float f32x4;
typedef __attribute__((ext_vector_type(8))) short s16x8;

#define DIM 512
#define GRIDB 256
#define SITES 8

__device__ __forceinline__ short f2bf(float f) {
    unsigned int u = __builtin_bit_cast(unsigned int, f);
    u += 0x7fffu + ((u >> 16) & 1u);
    return (short)(u >> 16);
}
__device__ __forceinline__ f32x4 ntld4(const float* p) {
    return __builtin_nontemporal_load((const f32x4*)p);
}
__device__ __forceinline__ s16x8 pack8(f32x4 a, f32x4 b) {
    s16x8 v;
    v[0] = f2bf(a[0]); v[1] = f2bf(a[1]); v[2] = f2bf(a[2]); v[3] = f2bf(a[3]);
    v[4] = f2bf(b[0]); v[5] = f2bf(b[1]); v[6] = f2bf(b[2]); v[7] = f2bf(b[3]);
    return v;
}
__device__ __forceinline__ int xaddr(int row, int kb) {   // 64x512 bf16, 1KiB rows
    return (row << 10) + (kb ^ ((row & 7) << 4));
}
__device__ __forceinline__ int taddr(int row, int kb) {   // 64x64 bf16, 128B rows
    return (row << 7) + (kb ^ ((row & 7) << 4));
}

// W pre-swizzle: frag chunk idx = (rowblk*16 + ks)*64 + lane -> one 1 KiB
// contiguous read per wave-fragment. q-scale (1/8) folded into Wq rows.
__global__ void conv_w(const float* __restrict__ w, unsigned short* __restrict__ wb) {
    int gid  = blockIdx.x * 256 + threadIdx.x;       // 0 .. 98303
    int lane = gid & 63;
    int ks   = (gid >> 6) & 15;
    int rowblk = gid >> 10;
    int row = rowblk * 16 + (lane & 15);
    int col = ks * 32 + (lane >> 4) * 8;
    const float* p = w + (size_t)row * DIM + col;
    f32x4 a = *(const f32x4*)p;
    f32x4 b = *(const f32x4*)(p + 4);
    float sc = (row < 512) ? 0.125f : 1.0f;
    a *= sc; b *= sc;
    *(s16x8*)(wb + (size_t)gid * 8) = pack8(a, b);
}

template<int WB16>
__device__ __forceinline__ s16x8 wfragL(const unsigned short* __restrict__ wb,
                                        const float* __restrict__ w,
                                        int rowblk, int ks, int lane) {
    if constexpr (WB16) {
        return *(const s16x8*)(wb + ((size_t)(rowblk * 16 + ks) * 64 + lane) * 8);
    } else {
        int row = rowblk * 16 + (lane & 15);
        int col = ks * 32 + (lane >> 4) * 8;
        const float* p = w + (size_t)row * DIM + col;
        f32x4 u0 = *(const f32x4*)p;
        f32x4 u1 = *(const f32x4*)(p + 4);
        float sc = (row < 512) ? 0.125f : 1.0f;
        u0 *= sc; u1 *= sc;
        return pack8(u0, u1);
    }
}

__device__ __forceinline__ bool decode_mask(const unsigned int* mk, int b) {
    unsigned int m0 = mk[0], m1 = mk[1];
    if (m0 <= 1u && m1 <= 1u) return ((b == 0) ? m0 : m1) != 0u;
    return ((const unsigned char*)mk)[b] != 0;
}

#define MFB(a, b, cc) __builtin_amdgcn_mfma_f32_16x16x32_bf16(a, b, cc, 0, 0, 0)

// X fragment reads (4 row-tiles at K-slice ks) from region base Xr
#define XF(ks)                                                              \
    s16x8 af0 = *(const s16x8*)(Xr + xaddr(c,      (ks) * 64 + g * 16));    \
    s16x8 af1 = *(const s16x8*)(Xr + xaddr(16 + c, (ks) * 64 + g * 16));    \
    s16x8 af2 = *(const s16x8*)(Xr + xaddr(32 + c, (ks) * 64 + g * 16));    \
    s16x8 af3 = *(const s16x8*)(Xr + xaddr(48 + c, (ks) * 64 + g * 16));

#define QKSTEP(ks)                                                          \
{                                                                           \
    s16x8 wq0 = wfragL<WB16>(wb, w, RQ,     (ks), lane);                    \
    s16x8 wq1 = wfragL<WB16>(wb, w, RQ + 1, (ks), lane);                    \
    s16x8 wk0 = wfragL<WB16>(wb, w, RK,     (ks), lane);                    \
    s16x8 wk1 = wfragL<WB16>(wb, w, RK + 1, (ks), lane);                    \
    XF(ks)                                                                  \
    qa[0][0]=MFB(af0,wq0,qa[0][0]); qa[0][1]=MFB(af0,wq1,qa[0][1]);         \
    qa[1][0]=MFB(af1,wq0,qa[1][0]); qa[1][1]=MFB(af1,wq1,qa[1][1]);         \
    qa[2][0]=MFB(af2,wq0,qa[2][0]); qa[2][1]=MFB(af2,wq1,qa[2][1]);         \
    qa[3][0]=MFB(af3,wq0,qa[3][0]); qa[3][1]=MFB(af3,wq1,qa[3][1]);         \
    ka[0][0]=MFB(af0,wk0,ka[0][0]); ka[0][1]=MFB(af0,wk1,ka[0][1]);         \
    ka[1][0]=MFB(af1,wk0,ka[1][0]); ka[1][1]=MFB(af1,wk1,ka[1][1]);         \
    ka[2][0]=MFB(af2,wk0,ka[2][0]); ka[2][1]=MFB(af2,wk1,ka[2][1]);         \
    ka[3][0]=MFB(af3,wk0,ka[3][0]); ka[3][1]=MFB(af3,wk1,ka[3][1]);         \
}

#define VSTEP(ks)                                                           \
{                                                                           \
    s16x8 wv0 = wfragL<WB16>(wb, w, RV,     (ks), lane);                    \
    s16x8 wv1 = wfragL<WB16>(wb, w, RV + 1, (ks), lane);                    \
    XF(ks)                                                                  \
    va[0][0]=MFB(wv0,af0,va[0][0]); va[0][1]=MFB(wv0,af1,va[0][1]);         \
    va[0][2]=MFB(wv0,af2,va[0][2]); va[0][3]=MFB(wv0,af3,va[0][3]);         \
    va[1][0]=MFB(wv1,af0,va[1][0]); va[1][1]=MFB(wv1,af1,va[1][1]);         \
    va[1][2]=MFB(wv1,af2,va[1][2]); va[1][3]=MFB(wv1,af3,va[1][3]);         \
}

#define PF_ISSUE(A0, A1, pi) \
    if (havenext) { A0 = ntld4(xnext + (pi) * 8); A1 = ntld4(xnext + (pi) * 8 + 4); }
#define PF_WRITE(A0, A1, pi) \
    if (havenext) { *(s16x8*)(Pr + xaddr(prow, pcp * 64 + (pi) * 16)) = pack8(A0, A1); }

template<int WB16>
__global__ __launch_bounds__(1024, 4)
void attn_all(const float* __restrict__ x,
              const float* __restrict__ w,
              const unsigned short* __restrict__ wb,
              const float* __restrict__ pb,
              const unsigned int* __restrict__ mk,
              float* __restrict__ out)
{
    extern __shared__ char smem[];
    const int tid  = threadIdx.x;
    const int lane = tid & 63;
    const int wave = tid >> 6;          // 0..15
    const int g    = lane >> 4;
    const int c    = lane & 15;
    const int hp   = wave >> 1;         // producer head
    const int hw2  = wave & 1;          // producer dh-half
    const int RQ = hp * 4 + 2 * hw2;
    const int RK = 32 + hp * 4 + 2 * hw2;
    const int RV = 64 + hp * 4 + 2 * hw2;
    const int prow = tid >> 4;          // staging row 0..63
    const int pcp  = tid & 15;          // staging col-chunk (32 floats)

    // prologue: stage site0 -> region 0
    {
        const float* gp = x + (size_t)blockIdx.x * (64 * DIM) + prow * DIM + pcp * 32;
        f32x4 f0 = ntld4(gp),      f1 = ntld4(gp + 4);
        f32x4 f2 = ntld4(gp + 8),  f3 = ntld4(gp + 12);
        f32x4 f4 = ntld4(gp + 16), f5 = ntld4(gp + 20);
        f32x4 f6 = ntld4(gp + 24), f7 = ntld4(gp + 28);
        *(s16x8*)(smem + xaddr(prow, pcp * 64))      = pack8(f0, f1);
        *(s16x8*)(smem + xaddr(prow, pcp * 64 + 16)) = pack8(f2, f3);
        *(s16x8*)(smem + xaddr(prow, pcp * 64 + 32)) = pack8(f4, f5);
        *(s16x8*)(smem + xaddr(prow, pcp * 64 + 48)) = pack8(f6, f7);
    }

    const f32x4 zf = {0.f, 0.f, 0.f, 0.f};

    for (int s = 0; s < SITES; ++s) {
        const int cursite = blockIdx.x + s * GRIDB;
        char* Xr = smem + (s & 1) * 65536;
        char* Pr = smem + ((s & 1) ^ 1) * 65536;
        const bool focused  = decode_mask(mk, cursite >> 10);
        const bool havenext = (s + 1 < SITES);
        const float* xnext  = x + (size_t)(blockIdx.x + (s + 1) * GRIDB) * (64 * DIM)
                                + prow * DIM + pcp * 32;
        float* outblk = out + (size_t)cursite * (64 * DIM);

        __syncthreads();                 // X(s) ready; previous slots dead

        f32x4 pf0a, pf0b, pf1a, pf1b, pf2a, pf2b, pf3a, pf3b;

        if (!focused) {
            // ---------- q,k projection + x(s+1) prefetch ----------
            f32x4 qa[4][2], ka[4][2];
            #pragma unroll
            for (int i = 0; i < 4; ++i) {
                qa[i][0] = zf; qa[i][1] = zf; ka[i][0] = zf; ka[i][1] = zf;
            }
            PF_ISSUE(pf0a, pf0b, 0) QKSTEP(0)  QKSTEP(1)
            PF_ISSUE(pf1a, pf1b, 1) QKSTEP(2)  QKSTEP(3)
            PF_ISSUE(pf2a, pf2b, 2) QKSTEP(4)  QKSTEP(5)
            PF_ISSUE(pf3a, pf3b, 3) QKSTEP(6)  QKSTEP(7)
            PF_WRITE(pf0a, pf0b, 0) QKSTEP(8)  QKSTEP(9)
            PF_WRITE(pf1a, pf1b, 1) QKSTEP(10) QKSTEP(11)
            PF_WRITE(pf2a, pf2b, 2) QKSTEP(12) QKSTEP(13)
            PF_WRITE(pf3a, pf3b, 3) QKSTEP(14) QKSTEP(15)

            // ---------- v projection ----------
            f32x4 va[2][4];
            #pragma unroll
            for (int j = 0; j < 4; ++j) { va[0][j] = zf; va[1][j] = zf; }
            VSTEP(0)  VSTEP(1)  VSTEP(2)  VSTEP(3)
            VSTEP(4)  VSTEP(5)  VSTEP(6)  VSTEP(7)
            VSTEP(8)  VSTEP(9)  VSTEP(10) VSTEP(11)
            VSTEP(12) VSTEP(13) VSTEP(14) VSTEP(15)

            // compress q,k,vT to bf16 regs (frees 48 VGPRs for round-1 holders)
            s16x8 qc[4], kc[4], vc[4];
            #pragma unroll
            for (int t = 0; t < 4; ++t) {
                qc[t] = pack8(qa[t][0], qa[t][1]);
                kc[t] = pack8(ka[t][0], ka[t][1]);
                vc[t] = pack8(va[0][t], va[1][t]);
            }

            __syncthreads();             // B1: X(s) reads done -> slots

            char* pqs = Xr + (hp & 3) * 16384;          // producer q / vT slot
            char* pks = pqs + 8192;                     // producer k / attn slot

            #pragma unroll
            for (int r = 0; r < 2; ++r) {
                if ((wave >> 3) == r) {
                    // write q,k: row = t*16+g*4+rr, col = hw2*32 + hc*16 + c
                    #pragma unroll
                    for (int t = 0; t < 4; ++t)
                        #pragma unroll
                        for (int hc = 0; hc < 2; ++hc)
                            #pragma unroll
                            for (int rr = 0; rr < 4; ++rr) {
                                int row = t * 16 + g * 4 + rr;
                                int col = hw2 * 32 + hc * 16 + c;
                                int off = (row << 7) + ((col * 2) ^ ((row & 7) << 4));
                                *(short*)(pqs + off) = qc[t][hc * 4 + rr];
                                *(short*)(pks + off) = kc[t][hc * 4 + rr];
                            }
                }
                __syncthreads();         // B2: q,k visible

                const int h  = r * 4 + (wave >> 2);     // attn-role head
                const int qt = wave & 3;                // token quarter
                char* aqs = Xr + (h & 3) * 16384;
                char* aks = aqs + 8192;

                // sim = q . k^T for rows [16qt,16qt+16)
                f32x4 sm[4] = {zf, zf, zf, zf};
                #pragma unroll
                for (int ks2 = 0; ks2 < 2; ++ks2) {
                    s16x8 aq  = *(const s16x8*)(aqs + taddr(qt * 16 + c, ks2 * 64 + g * 16));
                    s16x8 bk0 = *(const s16x8*)(aks + taddr(c,      ks2 * 64 + g * 16));
                    s16x8 bk1 = *(const s16x8*)(aks + taddr(16 + c, ks2 * 64 + g * 16));
                    s16x8 bk2 = *(const s16x8*)(aks + taddr(32 + c, ks2 * 64 + g * 16));
                    s16x8 bk3 = *(const s16x8*)(aks + taddr(48 + c, ks2 * 64 + g * 16));
                    sm[0] = MFB(aq, bk0, sm[0]); sm[1] = MFB(aq, bk1, sm[1]);
                    sm[2] = MFB(aq, bk2, sm[2]); sm[3] = MFB(aq, bk3, sm[3]);
                }

                // bias + softmax (reduce across c within 16-lane groups)
                const float* pbh = pb + h * 4096;
                #pragma unroll
                for (int rr = 0; rr < 4; ++rr) {
                    const int i = qt * 16 + g * 4 + rr;
                    float v0 = sm[0][rr] + pbh[i * 64 +  0 + c];
                    float v1 = sm[1][rr] + pbh[i * 64 + 16 + c];
                    float v2 = sm[2][rr] + pbh[i * 64 + 32 + c];
                    float v3 = sm[3][rr] + pbh[i * 64 + 48 + c];
                    float mx = fmaxf(fmaxf(v0, v1), fmaxf(v2, v3));
                    mx = fmaxf(mx, __shfl_xor(mx, 1));
                    mx = fmaxf(mx, __shfl_xor(mx, 2));
                    mx = fmaxf(mx, __shfl_xor(mx, 4));
                    mx = fmaxf(mx, __shfl_xor(mx, 8));
                    float p0 = __expf(v0 - mx);
                    float p1 = __expf(v1 - mx);
                    float p2 = __expf(v2 - mx);
                    float p3 = __expf(v3 - mx);
                    float ssum = p0 + p1 + p2 + p3;
                    ssum += __shfl_xor(ssum, 1);
                    ssum += __shfl_xor(ssum, 2);
                    ssum += __shfl_xor(ssum, 4);
                    ssum += __shfl_xor(ssum, 8);
                    float rinv = 1.0f / ssum;
                    sm[0][rr] = p0 * rinv; sm[1][rr] = p1 * rinv;
                    sm[2][rr] = p2 * rinv; sm[3][rr] = p3 * rinv;
                }
                __syncthreads();         // B3: q,k reads done

                if ((wave >> 3) == r) {
                    // vT -> q slot: row = hw2*32 + hf*16 + g*4 + rr, col = t*16+c
                    #pragma unroll
                    for (int t = 0; t < 4; ++t)
                        #pragma unroll
                        for (int hf = 0; hf < 2; ++hf)
                            #pragma unroll
                            for (int rr = 0; rr < 4; ++rr) {
                                int row = hw2 * 32 + hf * 16 + g * 4 + rr;
                                int col = t * 16 + c;
                                *(short*)(pqs + (row << 7) +
                                          ((col * 2) ^ ((row & 7) << 4))) =
                                    vc[t][hf * 4 + rr];
                            }
                }
                // attn -> k slot (own quarter rows)
                #pragma unroll
                for (int t = 0; t < 4; ++t)
                    #pragma unroll
                    for (int rr = 0; rr < 4; ++rr) {
                        int row = qt * 16 + g * 4 + rr;
                        int col = t * 16 + c;
                        *(short*)(aks + (row << 7) +
                                  ((col * 2) ^ ((row & 7) << 4))) = f2bf(sm[t][rr]);
                    }
                __syncthreads();         // B4: attn, vT visible

                // PV: C[dh][tok-quarter] = vT . attn^T, direct full-line store
                f32x4 ot0 = zf, ot1 = zf, ot2 = zf, ot3 = zf;
                #pragma unroll
                for (int ks2 = 0; ks2 < 2; ++ks2) {
                    s16x8 ba  = *(const s16x8*)(aks + taddr(qt * 16 + c, ks2 * 64 + g * 16));
                    s16x8 av0 = *(const s16x8*)(aqs + taddr(c,      ks2 * 64 + g * 16));
                    s16x8 av1 = *(const s16x8*)(aqs + taddr(16 + c, ks2 * 64 + g * 16));
                    s16x8 av2 = *(const s16x8*)(aqs + taddr(32 + c, ks2 * 64 + g * 16));
                    s16x8 av3 = *(const s16x8*)(aqs + taddr(48 + c, ks2 * 64 + g * 16));
                    ot0 = MFB(av0, ba, ot0); ot1 = MFB(av1, ba, ot1);
                    ot2 = MFB(av2, ba, ot2); ot3 = MFB(av3, ba, ot3);
                }
                {
                    float* ob = outblk + (size_t)(qt * 16 + c) * DIM + h * 64 + g * 4;
                    *(f32x4*)(ob)      = ot0;
                    *(f32x4*)(ob + 16) = ot1;
                    *(f32x4*)(ob + 32) = ot2;
                    *(f32x4*)(ob + 48) = ot3;
                }
                if (r == 0) __syncthreads();   // B5: slots dead before round 1
            }
        } else {
            // ---------- focused: out = v = X . Wv^T, prefetch rides v-loop ----------
            f32x4 va[2][4];
            #pragma unroll
            for (int j = 0; j < 4; ++j) { va[0][j] = zf; va[1][j] = zf; }
            PF_ISSUE(pf0a, pf0b, 0) VSTEP(0)  VSTEP(1)
            PF_ISSUE(pf1a, pf1b, 1) VSTEP(2)  VSTEP(3)
            PF_ISSUE(pf2a, pf2b, 2) VSTEP(4)  VSTEP(5)
            PF_ISSUE(pf3a, pf3b, 3) VSTEP(6)  VSTEP(7)
            PF_WRITE(pf0a, pf0b, 0) VSTEP(8)  VSTEP(9)
            PF_WRITE(pf1a, pf1b, 1) VSTEP(10) VSTEP(11)
            PF_WRITE(pf2a, pf2b, 2) VSTEP(12) VSTEP(13)
            PF_WRITE(pf3a, pf3b, 3) VSTEP(14) VSTEP(15)

            // direct store: out[tok=tc*16+c][hp*64 + hw2*32 + rt*16 + g*4 ..+4)
            #pragma unroll
            for (int rt = 0; rt < 2; ++rt)
                #pragma unroll
                for (int tc = 0; tc < 4; ++tc) {
                    float* dst = outblk + (size_t)(tc * 16 + c) * DIM
                                 + hp * 64 + hw2 * 32 + rt * 16 + g * 4;
                    *(f32x4*)dst = va[rt][tc];
                }
        }
    }
}

extern "C" void kernel_launch(void* const* d_in, const int* in_sizes, int n_in,
                              void* d_out, int out_size, void* d_ws, size_t ws_size,
                              hipStream_t stream)
{
    const float* x  = (const float*)d_in[0];
    const float* w  = (const float*)d_in[1];
    const float* pb = (const float*)d_in[2];
    const unsigned int* mk = (const unsigned int*)d_in[3];
    float* out = (float*)d_out;

    const int LDS = 131072;
    const size_t wbytes = (size_t)1536 * 512 * sizeof(unsigned short);

    if (ws_size >= wbytes) {
        unsigned short* wbp = (unsigned short*)d_ws;
        conv_w<<<dim3(384), dim3(256), 0, stream>>>(w, wbp);
        hipFuncSetAttribute(reinterpret_cast<const void*>(&attn_all<1>),
                            hipFuncAttributeMaxDynamicSharedMemorySize, LDS);
        attn_all<1><<<dim3(GRIDB), dim3(1024), LDS, stream>>>(x, w, wbp, pb, mk, out);
    } else {
        hipFuncSetAttribute(reinterpret_cast<const void*>(&attn_all<0>),
                            hipFuncAttributeMaxDynamicSharedMemorySize, LDS);
        attn_all<0><<<dim3(GRIDB), dim3(1024), LDS, stream>>>(x, w, nullptr, pb, mk, out);
    }
}

// Round 6
// 1580.701 us; speedup vs baseline: 1.0978x; 1.0978x over previous
//
#include <hip/hip_runtime.h>
#include <hip/hip_bf16.h>

// ---------------------------------------------------------------------------
// Round 6: R5 persistent pipeline, register-pressure-fixed.
// __launch_bounds__(1024,1) (2nd arg = min BLOCKS/CU -> VGPR cap 128, not 64).
// Projection split into Q/K/V passes (one 32-reg acc live at a time);
// 2-chunk in-flight x(s+1) prefetch (issue-early/write-late) rides the Q-pass.
//   x:(2,1024,64,512) f32  w:(1536,512) f32  pb:(8,64,64) f32  mk:(2,) bool
// ---------------------------------------------------------------------------

typedef __attribute__((ext_vector_type(4))) float f32x4;
typedef __attribute__((ext_vector_type(8))) short s16x8;

#define DIM 512
#define GRIDB 256
#define SITES 8

__device__ __forceinline__ short f2bf(float f) {
    unsigned int u = __builtin_bit_cast(unsigned int, f);
    u += 0x7fffu + ((u >> 16) & 1u);
    return (short)(u >> 16);
}
__device__ __forceinline__ f32x4 ntld4(const float* p) {
    return __builtin_nontemporal_load((const f32x4*)p);
}
__device__ __forceinline__ s16x8 pack8(f32x4 a, f32x4 b) {
    s16x8 v;
    v[0] = f2bf(a[0]); v[1] = f2bf(a[1]); v[2] = f2bf(a[2]); v[3] = f2bf(a[3]);
    v[4] = f2bf(b[0]); v[5] = f2bf(b[1]); v[6] = f2bf(b[2]); v[7] = f2bf(b[3]);
    return v;
}
__device__ __forceinline__ int xaddr(int row, int kb) {   // 64x512 bf16, 1KiB rows
    return (row << 10) + (kb ^ ((row & 7) << 4));
}
__device__ __forceinline__ int taddr(int row, int kb) {   // 64x64 bf16, 128B rows
    return (row << 7) + (kb ^ ((row & 7) << 4));
}

// W pre-swizzle: frag chunk idx = (rowblk*16 + ks)*64 + lane -> one 1 KiB
// contiguous read per wave-fragment. q-scale (1/8) folded into Wq rows.
__global__ void conv_w(const float* __restrict__ w, unsigned short* __restrict__ wb) {
    int gid  = blockIdx.x * 256 + threadIdx.x;       // 0 .. 98303
    int lane = gid & 63;
    int ks   = (gid >> 6) & 15;
    int rowblk = gid >> 10;
    int row = rowblk * 16 + (lane & 15);
    int col = ks * 32 + (lane >> 4) * 8;
    const float* p = w + (size_t)row * DIM + col;
    f32x4 a = *(const f32x4*)p;
    f32x4 b = *(const f32x4*)(p + 4);
    float sc = (row < 512) ? 0.125f : 1.0f;
    a *= sc; b *= sc;
    *(s16x8*)(wb + (size_t)gid * 8) = pack8(a, b);
}

template<int WB16>
__device__ __forceinline__ s16x8 wfragL(const unsigned short* __restrict__ wb,
                                        const float* __restrict__ w,
                                        int rowblk, int ks, int lane) {
    if constexpr (WB16) {
        return *(const s16x8*)(wb + ((size_t)(rowblk * 16 + ks) * 64 + lane) * 8);
    } else {
        int row = rowblk * 16 + (lane & 15);
        int col = ks * 32 + (lane >> 4) * 8;
        const float* p = w + (size_t)row * DIM + col;
        f32x4 u0 = *(const f32x4*)p;
        f32x4 u1 = *(const f32x4*)(p + 4);
        float sc = (row < 512) ? 0.125f : 1.0f;
        u0 *= sc; u1 *= sc;
        return pack8(u0, u1);
    }
}

__device__ __forceinline__ bool decode_mask(const unsigned int* mk, int b) {
    unsigned int m0 = mk[0], m1 = mk[1];
    if (m0 <= 1u && m1 <= 1u) return ((b == 0) ? m0 : m1) != 0u;
    return ((const unsigned char*)mk)[b] != 0;
}

#define MFB(a, b, cc) __builtin_amdgcn_mfma_f32_16x16x32_bf16(a, b, cc, 0, 0, 0)

// X fragment reads (4 row-tiles at K-slice ks) from region base Xr
#define XF(ks)                                                              \
    s16x8 af0 = *(const s16x8*)(Xr + xaddr(c,      (ks) * 64 + g * 16));    \
    s16x8 af1 = *(const s16x8*)(Xr + xaddr(16 + c, (ks) * 64 + g * 16));    \
    s16x8 af2 = *(const s16x8*)(Xr + xaddr(32 + c, (ks) * 64 + g * 16));    \
    s16x8 af3 = *(const s16x8*)(Xr + xaddr(48 + c, (ks) * 64 + g * 16));

// single-output projection pass step: acc[4][2] += X . W(rb..rb+1)^T
#define PSTEP(acc, rb, ks)                                                  \
{                                                                           \
    s16x8 w0 = wfragL<WB16>(wb, w, (rb),     (ks), lane);                   \
    s16x8 w1 = wfragL<WB16>(wb, w, (rb) + 1, (ks), lane);                   \
    XF(ks)                                                                  \
    acc[0][0]=MFB(af0,w0,acc[0][0]); acc[0][1]=MFB(af0,w1,acc[0][1]);       \
    acc[1][0]=MFB(af1,w0,acc[1][0]); acc[1][1]=MFB(af1,w1,acc[1][1]);       \
    acc[2][0]=MFB(af2,w0,acc[2][0]); acc[2][1]=MFB(af2,w1,acc[2][1]);       \
    acc[3][0]=MFB(af3,w0,acc[3][0]); acc[3][1]=MFB(af3,w1,acc[3][1]);       \
}

// vT pass step: va[2][4] += W(rv..rv+1) . X^T
#define VSTEP(ks)                                                           \
{                                                                           \
    s16x8 wv0 = wfragL<WB16>(wb, w, RV,     (ks), lane);                    \
    s16x8 wv1 = wfragL<WB16>(wb, w, RV + 1, (ks), lane);                    \
    XF(ks)                                                                  \
    va[0][0]=MFB(wv0,af0,va[0][0]); va[0][1]=MFB(wv0,af1,va[0][1]);         \
    va[0][2]=MFB(wv0,af2,va[0][2]); va[0][3]=MFB(wv0,af3,va[0][3]);         \
    va[1][0]=MFB(wv1,af0,va[1][0]); va[1][1]=MFB(wv1,af1,va[1][1]);         \
    va[1][2]=MFB(wv1,af2,va[1][2]); va[1][3]=MFB(wv1,af3,va[1][3]);         \
}

#define PFI(N, pi) \
    if (havenext) { N##0 = ntld4(xnext + (pi) * 8); N##1 = ntld4(xnext + (pi) * 8 + 4); }
#define PFW(N, pi) \
    if (havenext) { *(s16x8*)(Pr + xaddr(prow, pcp * 64 + (pi) * 16)) = pack8(N##0, N##1); }

template<int WB16>
__global__ __launch_bounds__(1024, 1)
void attn_all(const float* __restrict__ x,
              const float* __restrict__ w,
              const unsigned short* __restrict__ wb,
              const float* __restrict__ pb,
              const unsigned int* __restrict__ mk,
              float* __restrict__ out)
{
    extern __shared__ char smem[];
    const int tid  = threadIdx.x;
    const int lane = tid & 63;
    const int wave = tid >> 6;          // 0..15
    const int g    = lane >> 4;
    const int c    = lane & 15;
    const int hp   = wave >> 1;         // producer head
    const int hw2  = wave & 1;          // producer dh-half
    const int RQ = hp * 4 + 2 * hw2;
    const int RK = 32 + hp * 4 + 2 * hw2;
    const int RV = 64 + hp * 4 + 2 * hw2;
    const int prow = tid >> 4;          // staging row 0..63
    const int pcp  = tid & 15;          // staging col-chunk (32 floats)

    // prologue: stage site0 -> region 0
    {
        const float* gp = x + (size_t)blockIdx.x * (64 * DIM) + prow * DIM + pcp * 32;
        f32x4 f0 = ntld4(gp),      f1 = ntld4(gp + 4);
        f32x4 f2 = ntld4(gp + 8),  f3 = ntld4(gp + 12);
        f32x4 f4 = ntld4(gp + 16), f5 = ntld4(gp + 20);
        f32x4 f6 = ntld4(gp + 24), f7 = ntld4(gp + 28);
        *(s16x8*)(smem + xaddr(prow, pcp * 64))      = pack8(f0, f1);
        *(s16x8*)(smem + xaddr(prow, pcp * 64 + 16)) = pack8(f2, f3);
        *(s16x8*)(smem + xaddr(prow, pcp * 64 + 32)) = pack8(f4, f5);
        *(s16x8*)(smem + xaddr(prow, pcp * 64 + 48)) = pack8(f6, f7);
    }

    const f32x4 zf = {0.f, 0.f, 0.f, 0.f};

    for (int s = 0; s < SITES; ++s) {
        const int cursite = blockIdx.x + s * GRIDB;
        char* Xr = smem + (s & 1) * 65536;
        char* Pr = smem + ((s & 1) ^ 1) * 65536;
        const bool focused  = decode_mask(mk, cursite >> 10);
        const bool havenext = (s + 1 < SITES);
        const float* xnext  = x + (size_t)(blockIdx.x + (s + 1) * GRIDB) * (64 * DIM)
                                + prow * DIM + pcp * 32;
        float* outblk = out + (size_t)cursite * (64 * DIM);

        __syncthreads();                 // X(s) ready; previous slots dead

        f32x4 pfA0, pfA1, pfB0, pfB1;

        if (!focused) {
            // ---------- Q pass (+ x(s+1) prefetch, 2 chunks in flight) ----------
            f32x4 acc[4][2];
            #pragma unroll
            for (int i = 0; i < 4; ++i) { acc[i][0] = zf; acc[i][1] = zf; }
            PFI(pfA, 0) PSTEP(acc, RQ, 0)  PSTEP(acc, RQ, 1)  PSTEP(acc, RQ, 2)
            PFI(pfB, 1) PSTEP(acc, RQ, 3)  PSTEP(acc, RQ, 4)  PSTEP(acc, RQ, 5)
            PFW(pfA, 0) PSTEP(acc, RQ, 6)
            PFI(pfA, 2) PSTEP(acc, RQ, 7)  PSTEP(acc, RQ, 8)  PSTEP(acc, RQ, 9)
            PFW(pfB, 1) PSTEP(acc, RQ, 10)
            PFI(pfB, 3) PSTEP(acc, RQ, 11) PSTEP(acc, RQ, 12) PSTEP(acc, RQ, 13)
            PFW(pfA, 2) PSTEP(acc, RQ, 14) PSTEP(acc, RQ, 15)
            s16x8 qc[4];
            #pragma unroll
            for (int t = 0; t < 4; ++t) qc[t] = pack8(acc[t][0], acc[t][1]);

            // ---------- K pass ----------
            #pragma unroll
            for (int i = 0; i < 4; ++i) { acc[i][0] = zf; acc[i][1] = zf; }
            PSTEP(acc, RK, 0)
            PFW(pfB, 3)
            PSTEP(acc, RK, 1)  PSTEP(acc, RK, 2)  PSTEP(acc, RK, 3)
            PSTEP(acc, RK, 4)  PSTEP(acc, RK, 5)  PSTEP(acc, RK, 6)
            PSTEP(acc, RK, 7)  PSTEP(acc, RK, 8)  PSTEP(acc, RK, 9)
            PSTEP(acc, RK, 10) PSTEP(acc, RK, 11) PSTEP(acc, RK, 12)
            PSTEP(acc, RK, 13) PSTEP(acc, RK, 14) PSTEP(acc, RK, 15)
            s16x8 kc[4];
            #pragma unroll
            for (int t = 0; t < 4; ++t) kc[t] = pack8(acc[t][0], acc[t][1]);

            // ---------- V pass (vT) ----------
            f32x4 va[2][4];
            #pragma unroll
            for (int j = 0; j < 4; ++j) { va[0][j] = zf; va[1][j] = zf; }
            VSTEP(0)  VSTEP(1)  VSTEP(2)  VSTEP(3)
            VSTEP(4)  VSTEP(5)  VSTEP(6)  VSTEP(7)
            VSTEP(8)  VSTEP(9)  VSTEP(10) VSTEP(11)
            VSTEP(12) VSTEP(13) VSTEP(14) VSTEP(15)
            s16x8 vc[4];
            #pragma unroll
            for (int t = 0; t < 4; ++t) vc[t] = pack8(va[0][t], va[1][t]);

            __syncthreads();             // B1: X(s) reads done -> slots

            char* pqs = Xr + (hp & 3) * 16384;          // producer q / vT slot
            char* pks = pqs + 8192;                     // producer k / attn slot

            #pragma unroll
            for (int r = 0; r < 2; ++r) {
                if ((wave >> 3) == r) {
                    // write q,k: row = t*16+g*4+rr, col = hw2*32 + hc*16 + c
                    #pragma unroll
                    for (int t = 0; t < 4; ++t)
                        #pragma unroll
                        for (int hc = 0; hc < 2; ++hc)
                            #pragma unroll
                            for (int rr = 0; rr < 4; ++rr) {
                                int row = t * 16 + g * 4 + rr;
                                int col = hw2 * 32 + hc * 16 + c;
                                int off = (row << 7) + ((col * 2) ^ ((row & 7) << 4));
                                *(short*)(pqs + off) = qc[t][hc * 4 + rr];
                                *(short*)(pks + off) = kc[t][hc * 4 + rr];
                            }
                }
                __syncthreads();         // B2: q,k visible

                const int h  = r * 4 + (wave >> 2);     // attn-role head
                const int qt = wave & 3;                // token quarter
                char* aqs = Xr + (h & 3) * 16384;
                char* aks = aqs + 8192;

                // sim = q . k^T for rows [16qt,16qt+16)
                f32x4 sm[4] = {zf, zf, zf, zf};
                #pragma unroll
                for (int ks2 = 0; ks2 < 2; ++ks2) {
                    s16x8 aq  = *(const s16x8*)(aqs + taddr(qt * 16 + c, ks2 * 64 + g * 16));
                    s16x8 bk0 = *(const s16x8*)(aks + taddr(c,      ks2 * 64 + g * 16));
                    s16x8 bk1 = *(const s16x8*)(aks + taddr(16 + c, ks2 * 64 + g * 16));
                    s16x8 bk2 = *(const s16x8*)(aks + taddr(32 + c, ks2 * 64 + g * 16));
                    s16x8 bk3 = *(const s16x8*)(aks + taddr(48 + c, ks2 * 64 + g * 16));
                    sm[0] = MFB(aq, bk0, sm[0]); sm[1] = MFB(aq, bk1, sm[1]);
                    sm[2] = MFB(aq, bk2, sm[2]); sm[3] = MFB(aq, bk3, sm[3]);
                }

                // bias + softmax (reduce across c within 16-lane groups)
                const float* pbh = pb + h * 4096;
                #pragma unroll
                for (int rr = 0; rr < 4; ++rr) {
                    const int i = qt * 16 + g * 4 + rr;
                    float v0 = sm[0][rr] + pbh[i * 64 +  0 + c];
                    float v1 = sm[1][rr] + pbh[i * 64 + 16 + c];
                    float v2 = sm[2][rr] + pbh[i * 64 + 32 + c];
                    float v3 = sm[3][rr] + pbh[i * 64 + 48 + c];
                    float mx = fmaxf(fmaxf(v0, v1), fmaxf(v2, v3));
                    mx = fmaxf(mx, __shfl_xor(mx, 1));
                    mx = fmaxf(mx, __shfl_xor(mx, 2));
                    mx = fmaxf(mx, __shfl_xor(mx, 4));
                    mx = fmaxf(mx, __shfl_xor(mx, 8));
                    float p0 = __expf(v0 - mx);
                    float p1 = __expf(v1 - mx);
                    float p2 = __expf(v2 - mx);
                    float p3 = __expf(v3 - mx);
                    float ssum = p0 + p1 + p2 + p3;
                    ssum += __shfl_xor(ssum, 1);
                    ssum += __shfl_xor(ssum, 2);
                    ssum += __shfl_xor(ssum, 4);
                    ssum += __shfl_xor(ssum, 8);
                    float rinv = 1.0f / ssum;
                    sm[0][rr] = p0 * rinv; sm[1][rr] = p1 * rinv;
                    sm[2][rr] = p2 * rinv; sm[3][rr] = p3 * rinv;
                }
                __syncthreads();         // B3: q,k reads done

                if ((wave >> 3) == r) {
                    // vT -> q slot: row = hw2*32 + hf*16 + g*4 + rr, col = t*16+c
                    #pragma unroll
                    for (int t = 0; t < 4; ++t)
                        #pragma unroll
                        for (int hf = 0; hf < 2; ++hf)
                            #pragma unroll
                            for (int rr = 0; rr < 4; ++rr) {
                                int row = hw2 * 32 + hf * 16 + g * 4 + rr;
                                int col = t * 16 + c;
                                *(short*)(pqs + (row << 7) +
                                          ((col * 2) ^ ((row & 7) << 4))) =
                                    vc[t][hf * 4 + rr];
                            }
                }
                // attn -> k slot (own quarter rows)
                #pragma unroll
                for (int t = 0; t < 4; ++t)
                    #pragma unroll
                    for (int rr = 0; rr < 4; ++rr) {
                        int row = qt * 16 + g * 4 + rr;
                        int col = t * 16 + c;
                        *(short*)(aks + (row << 7) +
                                  ((col * 2) ^ ((row & 7) << 4))) = f2bf(sm[t][rr]);
                    }
                __syncthreads();         // B4: attn, vT visible

                // PV: C[dh][tok-quarter] = vT . attn^T, direct full-line store
                f32x4 ot0 = zf, ot1 = zf, ot2 = zf, ot3 = zf;
                #pragma unroll
                for (int ks2 = 0; ks2 < 2; ++ks2) {
                    s16x8 ba  = *(const s16x8*)(aks + taddr(qt * 16 + c, ks2 * 64 + g * 16));
                    s16x8 av0 = *(const s16x8*)(aqs + taddr(c,      ks2 * 64 + g * 16));
                    s16x8 av1 = *(const s16x8*)(aqs + taddr(16 + c, ks2 * 64 + g * 16));
                    s16x8 av2 = *(const s16x8*)(aqs + taddr(32 + c, ks2 * 64 + g * 16));
                    s16x8 av3 = *(const s16x8*)(aqs + taddr(48 + c, ks2 * 64 + g * 16));
                    ot0 = MFB(av0, ba, ot0); ot1 = MFB(av1, ba, ot1);
                    ot2 = MFB(av2, ba, ot2); ot3 = MFB(av3, ba, ot3);
                }
                {
                    float* ob = outblk + (size_t)(qt * 16 + c) * DIM + h * 64 + g * 4;
                    *(f32x4*)(ob)      = ot0;
                    *(f32x4*)(ob + 16) = ot1;
                    *(f32x4*)(ob + 32) = ot2;
                    *(f32x4*)(ob + 48) = ot3;
                }
                if (r == 0) __syncthreads();   // B5: slots dead before round 1
            }
        } else {
            // ---------- focused: out = v = X . Wv^T, prefetch rides v-loop ----------
            f32x4 va[2][4];
            #pragma unroll
            for (int j = 0; j < 4; ++j) { va[0][j] = zf; va[1][j] = zf; }
            PFI(pfA, 0) VSTEP(0)  VSTEP(1)  VSTEP(2)
            PFI(pfB, 1) VSTEP(3)  VSTEP(4)  VSTEP(5)
            PFW(pfA, 0) VSTEP(6)
            PFI(pfA, 2) VSTEP(7)  VSTEP(8)  VSTEP(9)
            PFW(pfB, 1) VSTEP(10)
            PFI(pfB, 3) VSTEP(11) VSTEP(12) VSTEP(13)
            PFW(pfA, 2) VSTEP(14) VSTEP(15)
            PFW(pfB, 3)

            // direct store: out[tok=tc*16+c][hp*64 + hw2*32 + rt*16 + g*4 ..+4)
            #pragma unroll
            for (int rt = 0; rt < 2; ++rt)
                #pragma unroll
                for (int tc = 0; tc < 4; ++tc) {
                    float* dst = outblk + (size_t)(tc * 16 + c) * DIM
                                 + hp * 64 + hw2 * 32 + rt * 16 + g * 4;
                    *(f32x4*)dst = va[rt][tc];
                }
        }
    }
}

extern "C" void kernel_launch(void* const* d_in, const int* in_sizes, int n_in,
                              void* d_out, int out_size, void* d_ws, size_t ws_size,
                              hipStream_t stream)
{
    const float* x  = (const float*)d_in[0];
    const float* w  = (const float*)d_in[1];
    const float* pb = (const float*)d_in[2];
    const unsigned int* mk = (const unsigned int*)d_in[3];
    float* out = (float*)d_out;

    const int LDS = 131072;
    const size_t wbytes = (size_t)1536 * 512 * sizeof(unsigned short);

    if (ws_size >= wbytes) {
        unsigned short* wbp = (unsigned short*)d_ws;
        conv_w<<<dim3(384), dim3(256), 0, stream>>>(w, wbp);
        hipFuncSetAttribute(reinterpret_cast<const void*>(&attn_all<1>),
                            hipFuncAttributeMaxDynamicSharedMemorySize, LDS);
        attn_all<1><<<dim3(GRIDB), dim3(1024), LDS, stream>>>(x, w, wbp, pb, mk, out);
    } else {
        hipFuncSetAttribute(reinterpret_cast<const void*>(&attn_all<0>),
                            hipFuncAttributeMaxDynamicSharedMemorySize, LDS);
        attn_all<0><<<dim3(GRIDB), dim3(1024), LDS, stream>>>(x, w, nullptr, pb, mk, out);
    }
}

// Round 7
// 1565.866 us; speedup vs baseline: 1.1082x; 1.0095x over previous
//
#include <hip/hip_runtime.h>
#include <hip/hip_bf16.h>

// ---------------------------------------------------------------------------
// Round 7: R6 persistent pipeline + amdgpu_waves_per_eu(4,4).
// The compiler's occupancy heuristic targets 8 waves/EU for 1024-thr blocks
// (it can't see the 128 KiB dynamic LDS) and caps VGPRs at 64, spilling
// everything. waves_per_eu(4,4) pins the target to 4 waves/EU = 1 block/CU
// -> 128-VGPR budget. Out stores made non-temporal (W stays L2-resident).
//   x:(2,1024,64,512) f32  w:(1536,512) f32  pb:(8,64,64) f32  mk:(2,) bool
// ---------------------------------------------------------------------------

typedef __attribute__((ext_vector_type(4))) float f32x4;
typedef __attribute__((ext_vector_type(8))) short s16x8;

#define DIM 512
#define GRIDB 256
#define SITES 8

__device__ __forceinline__ short f2bf(float f) {
    unsigned int u = __builtin_bit_cast(unsigned int, f);
    u += 0x7fffu + ((u >> 16) & 1u);
    return (short)(u >> 16);
}
__device__ __forceinline__ f32x4 ntld4(const float* p) {
    return __builtin_nontemporal_load((const f32x4*)p);
}
__device__ __forceinline__ void ntst4(float* p, f32x4 v) {
    __builtin_nontemporal_store(v, (f32x4*)p);
}
__device__ __forceinline__ s16x8 pack8(f32x4 a, f32x4 b) {
    s16x8 v;
    v[0] = f2bf(a[0]); v[1] = f2bf(a[1]); v[2] = f2bf(a[2]); v[3] = f2bf(a[3]);
    v[4] = f2bf(b[0]); v[5] = f2bf(b[1]); v[6] = f2bf(b[2]); v[7] = f2bf(b[3]);
    return v;
}
__device__ __forceinline__ int xaddr(int row, int kb) {   // 64x512 bf16, 1KiB rows
    return (row << 10) + (kb ^ ((row & 7) << 4));
}
__device__ __forceinline__ int taddr(int row, int kb) {   // 64x64 bf16, 128B rows
    return (row << 7) + (kb ^ ((row & 7) << 4));
}

// W pre-swizzle: frag chunk idx = (rowblk*16 + ks)*64 + lane -> one 1 KiB
// contiguous read per wave-fragment. q-scale (1/8) folded into Wq rows.
__global__ void conv_w(const float* __restrict__ w, unsigned short* __restrict__ wb) {
    int gid  = blockIdx.x * 256 + threadIdx.x;       // 0 .. 98303
    int lane = gid & 63;
    int ks   = (gid >> 6) & 15;
    int rowblk = gid >> 10;
    int row = rowblk * 16 + (lane & 15);
    int col = ks * 32 + (lane >> 4) * 8;
    const float* p = w + (size_t)row * DIM + col;
    f32x4 a = *(const f32x4*)p;
    f32x4 b = *(const f32x4*)(p + 4);
    float sc = (row < 512) ? 0.125f : 1.0f;
    a *= sc; b *= sc;
    *(s16x8*)(wb + (size_t)gid * 8) = pack8(a, b);
}

template<int WB16>
__device__ __forceinline__ s16x8 wfragL(const unsigned short* __restrict__ wb,
                                        const float* __restrict__ w,
                                        int rowblk, int ks, int lane) {
    if constexpr (WB16) {
        return *(const s16x8*)(wb + ((size_t)(rowblk * 16 + ks) * 64 + lane) * 8);
    } else {
        int row = rowblk * 16 + (lane & 15);
        int col = ks * 32 + (lane >> 4) * 8;
        const float* p = w + (size_t)row * DIM + col;
        f32x4 u0 = *(const f32x4*)p;
        f32x4 u1 = *(const f32x4*)(p + 4);
        float sc = (row < 512) ? 0.125f : 1.0f;
        u0 *= sc; u1 *= sc;
        return pack8(u0, u1);
    }
}

__device__ __forceinline__ bool decode_mask(const unsigned int* mk, int b) {
    unsigned int m0 = mk[0], m1 = mk[1];
    if (m0 <= 1u && m1 <= 1u) return ((b == 0) ? m0 : m1) != 0u;
    return ((const unsigned char*)mk)[b] != 0;
}

#define MFB(a, b, cc) __builtin_amdgcn_mfma_f32_16x16x32_bf16(a, b, cc, 0, 0, 0)

// X fragment reads (4 row-tiles at K-slice ks) from region base Xr
#define XF(ks)                                                              \
    s16x8 af0 = *(const s16x8*)(Xr + xaddr(c,      (ks) * 64 + g * 16));    \
    s16x8 af1 = *(const s16x8*)(Xr + xaddr(16 + c, (ks) * 64 + g * 16));    \
    s16x8 af2 = *(const s16x8*)(Xr + xaddr(32 + c, (ks) * 64 + g * 16));    \
    s16x8 af3 = *(const s16x8*)(Xr + xaddr(48 + c, (ks) * 64 + g * 16));

// single-output projection pass step: acc[4][2] += X . W(rb..rb+1)^T
#define PSTEP(acc, rb, ks)                                                  \
{                                                                           \
    s16x8 w0 = wfragL<WB16>(wb, w, (rb),     (ks), lane);                   \
    s16x8 w1 = wfragL<WB16>(wb, w, (rb) + 1, (ks), lane);                   \
    XF(ks)                                                                  \
    acc[0][0]=MFB(af0,w0,acc[0][0]); acc[0][1]=MFB(af0,w1,acc[0][1]);       \
    acc[1][0]=MFB(af1,w0,acc[1][0]); acc[1][1]=MFB(af1,w1,acc[1][1]);       \
    acc[2][0]=MFB(af2,w0,acc[2][0]); acc[2][1]=MFB(af2,w1,acc[2][1]);       \
    acc[3][0]=MFB(af3,w0,acc[3][0]); acc[3][1]=MFB(af3,w1,acc[3][1]);       \
}

// vT pass step: va[2][4] += W(rv..rv+1) . X^T
#define VSTEP(ks)                                                           \
{                                                                           \
    s16x8 wv0 = wfragL<WB16>(wb, w, RV,     (ks), lane);                    \
    s16x8 wv1 = wfragL<WB16>(wb, w, RV + 1, (ks), lane);                    \
    XF(ks)                                                                  \
    va[0][0]=MFB(wv0,af0,va[0][0]); va[0][1]=MFB(wv0,af1,va[0][1]);         \
    va[0][2]=MFB(wv0,af2,va[0][2]); va[0][3]=MFB(wv0,af3,va[0][3]);         \
    va[1][0]=MFB(wv1,af0,va[1][0]); va[1][1]=MFB(wv1,af1,va[1][1]);         \
    va[1][2]=MFB(wv1,af2,va[1][2]); va[1][3]=MFB(wv1,af3,va[1][3]);         \
}

#define PFI(N, pi) \
    if (havenext) { N##0 = ntld4(xnext + (pi) * 8); N##1 = ntld4(xnext + (pi) * 8 + 4); }
#define PFW(N, pi) \
    if (havenext) { *(s16x8*)(Pr + xaddr(prow, pcp * 64 + (pi) * 16)) = pack8(N##0, N##1); }

template<int WB16>
__global__ __launch_bounds__(1024)
__attribute__((amdgpu_waves_per_eu(4, 4)))
void attn_all(const float* __restrict__ x,
              const float* __restrict__ w,
              const unsigned short* __restrict__ wb,
              const float* __restrict__ pb,
              const unsigned int* __restrict__ mk,
              float* __restrict__ out)
{
    extern __shared__ char smem[];
    const int tid  = threadIdx.x;
    const int lane = tid & 63;
    const int wave = tid >> 6;          // 0..15
    const int g    = lane >> 4;
    const int c    = lane & 15;
    const int hp   = wave >> 1;         // producer head
    const int hw2  = wave & 1;          // producer dh-half
    const int RQ = hp * 4 + 2 * hw2;
    const int RK = 32 + hp * 4 + 2 * hw2;
    const int RV = 64 + hp * 4 + 2 * hw2;
    const int prow = tid >> 4;          // staging row 0..63
    const int pcp  = tid & 15;          // staging col-chunk (32 floats)

    // prologue: stage site0 -> region 0
    {
        const float* gp = x + (size_t)blockIdx.x * (64 * DIM) + prow * DIM + pcp * 32;
        f32x4 f0 = ntld4(gp),      f1 = ntld4(gp + 4);
        f32x4 f2 = ntld4(gp + 8),  f3 = ntld4(gp + 12);
        f32x4 f4 = ntld4(gp + 16), f5 = ntld4(gp + 20);
        f32x4 f6 = ntld4(gp + 24), f7 = ntld4(gp + 28);
        *(s16x8*)(smem + xaddr(prow, pcp * 64))      = pack8(f0, f1);
        *(s16x8*)(smem + xaddr(prow, pcp * 64 + 16)) = pack8(f2, f3);
        *(s16x8*)(smem + xaddr(prow, pcp * 64 + 32)) = pack8(f4, f5);
        *(s16x8*)(smem + xaddr(prow, pcp * 64 + 48)) = pack8(f6, f7);
    }

    const f32x4 zf = {0.f, 0.f, 0.f, 0.f};

    for (int s = 0; s < SITES; ++s) {
        const int cursite = blockIdx.x + s * GRIDB;
        char* Xr = smem + (s & 1) * 65536;
        char* Pr = smem + ((s & 1) ^ 1) * 65536;
        const bool focused  = decode_mask(mk, cursite >> 10);
        const bool havenext = (s + 1 < SITES);
        const float* xnext  = x + (size_t)(blockIdx.x + (s + 1) * GRIDB) * (64 * DIM)
                                + prow * DIM + pcp * 32;
        float* outblk = out + (size_t)cursite * (64 * DIM);

        __syncthreads();                 // X(s) ready; previous slots dead

        f32x4 pfA0, pfA1, pfB0, pfB1;

        if (!focused) {
            // ---------- Q pass (+ x(s+1) prefetch, 2 chunks in flight) ----------
            f32x4 acc[4][2];
            #pragma unroll
            for (int i = 0; i < 4; ++i) { acc[i][0] = zf; acc[i][1] = zf; }
            PFI(pfA, 0) PSTEP(acc, RQ, 0)  PSTEP(acc, RQ, 1)  PSTEP(acc, RQ, 2)
            PFI(pfB, 1) PSTEP(acc, RQ, 3)  PSTEP(acc, RQ, 4)  PSTEP(acc, RQ, 5)
            PFW(pfA, 0) PSTEP(acc, RQ, 6)
            PFI(pfA, 2) PSTEP(acc, RQ, 7)  PSTEP(acc, RQ, 8)  PSTEP(acc, RQ, 9)
            PFW(pfB, 1) PSTEP(acc, RQ, 10)
            PFI(pfB, 3) PSTEP(acc, RQ, 11) PSTEP(acc, RQ, 12) PSTEP(acc, RQ, 13)
            PFW(pfA, 2) PSTEP(acc, RQ, 14) PSTEP(acc, RQ, 15)
            s16x8 qc[4];
            #pragma unroll
            for (int t = 0; t < 4; ++t) qc[t] = pack8(acc[t][0], acc[t][1]);

            // ---------- K pass ----------
            #pragma unroll
            for (int i = 0; i < 4; ++i) { acc[i][0] = zf; acc[i][1] = zf; }
            PSTEP(acc, RK, 0)
            PFW(pfB, 3)
            PSTEP(acc, RK, 1)  PSTEP(acc, RK, 2)  PSTEP(acc, RK, 3)
            PSTEP(acc, RK, 4)  PSTEP(acc, RK, 5)  PSTEP(acc, RK, 6)
            PSTEP(acc, RK, 7)  PSTEP(acc, RK, 8)  PSTEP(acc, RK, 9)
            PSTEP(acc, RK, 10) PSTEP(acc, RK, 11) PSTEP(acc, RK, 12)
            PSTEP(acc, RK, 13) PSTEP(acc, RK, 14) PSTEP(acc, RK, 15)
            s16x8 kc[4];
            #pragma unroll
            for (int t = 0; t < 4; ++t) kc[t] = pack8(acc[t][0], acc[t][1]);

            // ---------- V pass (vT) ----------
            f32x4 va[2][4];
            #pragma unroll
            for (int j = 0; j < 4; ++j) { va[0][j] = zf; va[1][j] = zf; }
            VSTEP(0)  VSTEP(1)  VSTEP(2)  VSTEP(3)
            VSTEP(4)  VSTEP(5)  VSTEP(6)  VSTEP(7)
            VSTEP(8)  VSTEP(9)  VSTEP(10) VSTEP(11)
            VSTEP(12) VSTEP(13) VSTEP(14) VSTEP(15)
            s16x8 vc[4];
            #pragma unroll
            for (int t = 0; t < 4; ++t) vc[t] = pack8(va[0][t], va[1][t]);

            __syncthreads();             // B1: X(s) reads done -> slots

            char* pqs = Xr + (hp & 3) * 16384;          // producer q / vT slot
            char* pks = pqs + 8192;                     // producer k / attn slot

            #pragma unroll
            for (int r = 0; r < 2; ++r) {
                if ((wave >> 3) == r) {
                    // write q,k: row = t*16+g*4+rr, col = hw2*32 + hc*16 + c
                    #pragma unroll
                    for (int t = 0; t < 4; ++t)
                        #pragma unroll
                        for (int hc = 0; hc < 2; ++hc)
                            #pragma unroll
                            for (int rr = 0; rr < 4; ++rr) {
                                int row = t * 16 + g * 4 + rr;
                                int col = hw2 * 32 + hc * 16 + c;
                                int off = (row << 7) + ((col * 2) ^ ((row & 7) << 4));
                                *(short*)(pqs + off) = qc[t][hc * 4 + rr];
                                *(short*)(pks + off) = kc[t][hc * 4 + rr];
                            }
                }
                __syncthreads();         // B2: q,k visible

                const int h  = r * 4 + (wave >> 2);     // attn-role head
                const int qt = wave & 3;                // token quarter
                char* aqs = Xr + (h & 3) * 16384;
                char* aks = aqs + 8192;

                // sim = q . k^T for rows [16qt,16qt+16)
                f32x4 sm[4] = {zf, zf, zf, zf};
                #pragma unroll
                for (int ks2 = 0; ks2 < 2; ++ks2) {
                    s16x8 aq  = *(const s16x8*)(aqs + taddr(qt * 16 + c, ks2 * 64 + g * 16));
                    s16x8 bk0 = *(const s16x8*)(aks + taddr(c,      ks2 * 64 + g * 16));
                    s16x8 bk1 = *(const s16x8*)(aks + taddr(16 + c, ks2 * 64 + g * 16));
                    s16x8 bk2 = *(const s16x8*)(aks + taddr(32 + c, ks2 * 64 + g * 16));
                    s16x8 bk3 = *(const s16x8*)(aks + taddr(48 + c, ks2 * 64 + g * 16));
                    sm[0] = MFB(aq, bk0, sm[0]); sm[1] = MFB(aq, bk1, sm[1]);
                    sm[2] = MFB(aq, bk2, sm[2]); sm[3] = MFB(aq, bk3, sm[3]);
                }

                // bias + softmax (reduce across c within 16-lane groups)
                const float* pbh = pb + h * 4096;
                #pragma unroll
                for (int rr = 0; rr < 4; ++rr) {
                    const int i = qt * 16 + g * 4 + rr;
                    float v0 = sm[0][rr] + pbh[i * 64 +  0 + c];
                    float v1 = sm[1][rr] + pbh[i * 64 + 16 + c];
                    float v2 = sm[2][rr] + pbh[i * 64 + 32 + c];
                    float v3 = sm[3][rr] + pbh[i * 64 + 48 + c];
                    float mx = fmaxf(fmaxf(v0, v1), fmaxf(v2, v3));
                    mx = fmaxf(mx, __shfl_xor(mx, 1));
                    mx = fmaxf(mx, __shfl_xor(mx, 2));
                    mx = fmaxf(mx, __shfl_xor(mx, 4));
                    mx = fmaxf(mx, __shfl_xor(mx, 8));
                    float p0 = __expf(v0 - mx);
                    float p1 = __expf(v1 - mx);
                    float p2 = __expf(v2 - mx);
                    float p3 = __expf(v3 - mx);
                    float ssum = p0 + p1 + p2 + p3;
                    ssum += __shfl_xor(ssum, 1);
                    ssum += __shfl_xor(ssum, 2);
                    ssum += __shfl_xor(ssum, 4);
                    ssum += __shfl_xor(ssum, 8);
                    float rinv = 1.0f / ssum;
                    sm[0][rr] = p0 * rinv; sm[1][rr] = p1 * rinv;
                    sm[2][rr] = p2 * rinv; sm[3][rr] = p3 * rinv;
                }
                __syncthreads();         // B3: q,k reads done

                if ((wave >> 3) == r) {
                    // vT -> q slot: row = hw2*32 + hf*16 + g*4 + rr, col = t*16+c
                    #pragma unroll
                    for (int t = 0; t < 4; ++t)
                        #pragma unroll
                        for (int hf = 0; hf < 2; ++hf)
                            #pragma unroll
                            for (int rr = 0; rr < 4; ++rr) {
                                int row = hw2 * 32 + hf * 16 + g * 4 + rr;
                                int col = t * 16 + c;
                                *(short*)(pqs + (row << 7) +
                                          ((col * 2) ^ ((row & 7) << 4))) =
                                    vc[t][hf * 4 + rr];
                            }
                }
                // attn -> k slot (own quarter rows)
                #pragma unroll
                for (int t = 0; t < 4; ++t)
                    #pragma unroll
                    for (int rr = 0; rr < 4; ++rr) {
                        int row = qt * 16 + g * 4 + rr;
                        int col = t * 16 + c;
                        *(short*)(aks + (row << 7) +
                                  ((col * 2) ^ ((row & 7) << 4))) = f2bf(sm[t][rr]);
                    }
                __syncthreads();         // B4: attn, vT visible

                // PV: C[dh][tok-quarter] = vT . attn^T, nt full-line store
                f32x4 ot0 = zf, ot1 = zf, ot2 = zf, ot3 = zf;
                #pragma unroll
                for (int ks2 = 0; ks2 < 2; ++ks2) {
                    s16x8 ba  = *(const s16x8*)(aks + taddr(qt * 16 + c, ks2 * 64 + g * 16));
                    s16x8 av0 = *(const s16x8*)(aqs + taddr(c,      ks2 * 64 + g * 16));
                    s16x8 av1 = *(const s16x8*)(aqs + taddr(16 + c, ks2 * 64 + g * 16));
                    s16x8 av2 = *(const s16x8*)(aqs + taddr(32 + c, ks2 * 64 + g * 16));
                    s16x8 av3 = *(const s16x8*)(aqs + taddr(48 + c, ks2 * 64 + g * 16));
                    ot0 = MFB(av0, ba, ot0); ot1 = MFB(av1, ba, ot1);
                    ot2 = MFB(av2, ba, ot2); ot3 = MFB(av3, ba, ot3);
                }
                {
                    float* ob = outblk + (size_t)(qt * 16 + c) * DIM + h * 64 + g * 4;
                    ntst4(ob,      ot0);
                    ntst4(ob + 16, ot1);
                    ntst4(ob + 32, ot2);
                    ntst4(ob + 48, ot3);
                }
                if (r == 0) __syncthreads();   // B5: slots dead before round 1
            }
        } else {
            // ---------- focused: out = v = X . Wv^T, prefetch rides v-loop ----------
            f32x4 va[2][4];
            #pragma unroll
            for (int j = 0; j < 4; ++j) { va[0][j] = zf; va[1][j] = zf; }
            PFI(pfA, 0) VSTEP(0)  VSTEP(1)  VSTEP(2)
            PFI(pfB, 1) VSTEP(3)  VSTEP(4)  VSTEP(5)
            PFW(pfA, 0) VSTEP(6)
            PFI(pfA, 2) VSTEP(7)  VSTEP(8)  VSTEP(9)
            PFW(pfB, 1) VSTEP(10)
            PFI(pfB, 3) VSTEP(11) VSTEP(12) VSTEP(13)
            PFW(pfA, 2) VSTEP(14) VSTEP(15)
            PFW(pfB, 3)

            // nt store: out[tok=tc*16+c][hp*64 + hw2*32 + rt*16 + g*4 ..+4)
            #pragma unroll
            for (int rt = 0; rt < 2; ++rt)
                #pragma unroll
                for (int tc = 0; tc < 4; ++tc) {
                    float* dst = outblk + (size_t)(tc * 16 + c) * DIM
                                 + hp * 64 + hw2 * 32 + rt * 16 + g * 4;
                    ntst4(dst, va[rt][tc]);
                }
        }
    }
}

extern "C" void kernel_launch(void* const* d_in, const int* in_sizes, int n_in,
                              void* d_out, int out_size, void* d_ws, size_t ws_size,
                              hipStream_t stream)
{
    const float* x  = (const float*)d_in[0];
    const float* w  = (const float*)d_in[1];
    const float* pb = (const float*)d_in[2];
    const unsigned int* mk = (const unsigned int*)d_in[3];
    float* out = (float*)d_out;

    const int LDS = 131072;
    const size_t wbytes = (size_t)1536 * 512 * sizeof(unsigned short);

    if (ws_size >= wbytes) {
        unsigned short* wbp = (unsigned short*)d_ws;
        conv_w<<<dim3(384), dim3(256), 0, stream>>>(w, wbp);
        hipFuncSetAttribute(reinterpret_cast<const void*>(&attn_all<1>),
                            hipFuncAttributeMaxDynamicSharedMemorySize, LDS);
        attn_all<1><<<dim3(GRIDB), dim3(1024), LDS, stream>>>(x, w, wbp, pb, mk, out);
    } else {
        hipFuncSetAttribute(reinterpret_cast<const void*>(&attn_all<0>),
                            hipFuncAttributeMaxDynamicSharedMemorySize, LDS);
        attn_all<0><<<dim3(GRIDB), dim3(1024), LDS, stream>>>(x, w, nullptr, pb, mk, out);
    }
}

// Round 8
// 454.612 us; speedup vs baseline: 3.8172x; 3.4444x over previous
//
#include <hip/hip_runtime.h>
#include <hip/hip_bf16.h>

// ---------------------------------------------------------------------------
// Round 8: persistent kernel on 512-thread blocks (the only shape that gets
// 128 VGPRs), 64 KiB LDS -> 2 blocks/CU for cross-block stage/compute overlap.
// Per site: stage X -> per-wave head projection (packed bf16 intermediates)
// -> barrier -> wave-private attention in the freed X region (8KiB slot/wave,
// lgkmcnt-ordered, no barriers) -> transposed PV -> full-line nt stores.
//   x:(2,1024,64,512) f32  w:(1536,512) f32  pb:(8,64,64) f32  mk:(2,) bool
// ---------------------------------------------------------------------------

typedef __attribute__((ext_vector_type(4))) float f32x4;
typedef __attribute__((ext_vector_type(8))) short s16x8;

#define DIM 512
#define GRIDB 512
#define SITES 4

__device__ __forceinline__ short f2bf(float f) {
    unsigned int u = __builtin_bit_cast(unsigned int, f);
    u += 0x7fffu + ((u >> 16) & 1u);
    return (short)(u >> 16);
}
__device__ __forceinline__ f32x4 ntld4(const float* p) {
    return __builtin_nontemporal_load((const f32x4*)p);
}
__device__ __forceinline__ void ntst4(float* p, f32x4 v) {
    __builtin_nontemporal_store(v, (f32x4*)p);
}
__device__ __forceinline__ s16x8 pack8(f32x4 a, f32x4 b) {
    s16x8 v;
    v[0] = f2bf(a[0]); v[1] = f2bf(a[1]); v[2] = f2bf(a[2]); v[3] = f2bf(a[3]);
    v[4] = f2bf(b[0]); v[5] = f2bf(b[1]); v[6] = f2bf(b[2]); v[7] = f2bf(b[3]);
    return v;
}
__device__ __forceinline__ int xaddr(int row, int kb) {   // 64x512 bf16, 1KiB rows
    return (row << 10) + (kb ^ ((row & 7) << 4));
}
__device__ __forceinline__ int taddr(int row, int kb) {   // 64x64 bf16, 128B rows
    return (row << 7) + (kb ^ ((row & 7) << 4));
}

// W pre-swizzle: frag chunk idx = (rowblk*16 + ks)*64 + lane -> one 1 KiB
// contiguous read per wave-fragment. q-scale (1/8) folded into Wq rows.
__global__ void conv_w(const float* __restrict__ w, unsigned short* __restrict__ wb) {
    int gid  = blockIdx.x * 256 + threadIdx.x;       // 0 .. 98303
    int lane = gid & 63;
    int ks   = (gid >> 6) & 15;
    int rowblk = gid >> 10;
    int row = rowblk * 16 + (lane & 15);
    int col = ks * 32 + (lane >> 4) * 8;
    const float* p = w + (size_t)row * DIM + col;
    f32x4 a = *(const f32x4*)p;
    f32x4 b = *(const f32x4*)(p + 4);
    float sc = (row < 512) ? 0.125f : 1.0f;
    a *= sc; b *= sc;
    *(s16x8*)(wb + (size_t)gid * 8) = pack8(a, b);
}

template<int WB16>
__device__ __forceinline__ s16x8 wfragL(const unsigned short* __restrict__ wb,
                                        const float* __restrict__ w,
                                        int rowblk, int ks, int lane) {
    if constexpr (WB16) {
        return *(const s16x8*)(wb + ((size_t)(rowblk * 16 + ks) * 64 + lane) * 8);
    } else {
        int row = rowblk * 16 + (lane & 15);
        int col = ks * 32 + (lane >> 4) * 8;
        const float* p = w + (size_t)row * DIM + col;
        f32x4 u0 = *(const f32x4*)p;
        f32x4 u1 = *(const f32x4*)(p + 4);
        float sc = (row < 512) ? 0.125f : 1.0f;
        u0 *= sc; u1 *= sc;
        return pack8(u0, u1);
    }
}

__device__ __forceinline__ bool decode_mask(const unsigned int* mk, int b) {
    unsigned int m0 = mk[0], m1 = mk[1];
    if (m0 <= 1u && m1 <= 1u) return ((b == 0) ? m0 : m1) != 0u;
    return ((const unsigned char*)mk)[b] != 0;
}

#define MFB(a, b, cc) __builtin_amdgcn_mfma_f32_16x16x32_bf16(a, b, cc, 0, 0, 0)

// X fragment reads (4 token-row tiles at K-slice ks) from X region (= smem)
#define XF(ks)                                                               \
    s16x8 af0 = *(const s16x8*)(smem + xaddr(c,      (ks) * 64 + g * 16));   \
    s16x8 af1 = *(const s16x8*)(smem + xaddr(16 + c, (ks) * 64 + g * 16));   \
    s16x8 af2 = *(const s16x8*)(smem + xaddr(32 + c, (ks) * 64 + g * 16));   \
    s16x8 af3 = *(const s16x8*)(smem + xaddr(48 + c, (ks) * 64 + g * 16));

template<int WB16>
__global__ __launch_bounds__(512, 2)
void attn_all(const float* __restrict__ x,
              const float* __restrict__ w,
              const unsigned short* __restrict__ wb,
              const float* __restrict__ pb,
              const unsigned int* __restrict__ mk,
              float* __restrict__ out)
{
    extern __shared__ char smem[];
    const int tid  = threadIdx.x;
    const int lane = tid & 63;
    const int wave = tid >> 6;          // 0..7 == head
    const int g    = lane >> 4;
    const int c    = lane & 15;
    const int srow = tid >> 3;          // staging row 0..63
    const int scc  = tid & 7;           // staging chunk (64 floats)
    char* slot = smem + wave * 8192;    // wave-private scratch after X retires
    const f32x4 zf = {0.f, 0.f, 0.f, 0.f};
    const int h = wave;

    for (int s = 0; s < SITES; ++s) {
        const int cursite = blockIdx.x + s * GRIDB;
        const bool focused = decode_mask(mk, cursite >> 10);
        const float* xblk   = x   + (size_t)cursite * (64 * DIM);
        float*       outblk = out + (size_t)cursite * (64 * DIM);

        __syncthreads();                 // previous site's scratch dead
        {   // stage X: 64x512 f32 -> bf16 swizzled (nt loads keep W in L2)
            const float* gp = xblk + srow * DIM + scc * 64;
            #pragma unroll
            for (int i = 0; i < 8; ++i) {
                f32x4 a = ntld4(gp + i * 8);
                f32x4 b = ntld4(gp + i * 8 + 4);
                *(s16x8*)(smem + xaddr(srow, scc * 128 + i * 16)) = pack8(a, b);
            }
        }
        __syncthreads();                 // X ready

        if (!focused) {
            s16x8 qc[2][4], kc[2][4], vq[4][2];

            // ---- Q projection, dh-halves ----
            #pragma unroll
            for (int hf = 0; hf < 2; ++hf) {
                const int RB = h * 4 + 2 * hf;
                f32x4 acc[4][2];
                #pragma unroll
                for (int t = 0; t < 4; ++t) { acc[t][0] = zf; acc[t][1] = zf; }
                #pragma unroll 4
                for (int ks = 0; ks < 16; ++ks) {
                    s16x8 w0 = wfragL<WB16>(wb, w, RB,     ks, lane);
                    s16x8 w1 = wfragL<WB16>(wb, w, RB + 1, ks, lane);
                    XF(ks)
                    acc[0][0]=MFB(af0,w0,acc[0][0]); acc[0][1]=MFB(af0,w1,acc[0][1]);
                    acc[1][0]=MFB(af1,w0,acc[1][0]); acc[1][1]=MFB(af1,w1,acc[1][1]);
                    acc[2][0]=MFB(af2,w0,acc[2][0]); acc[2][1]=MFB(af2,w1,acc[2][1]);
                    acc[3][0]=MFB(af3,w0,acc[3][0]); acc[3][1]=MFB(af3,w1,acc[3][1]);
                }
                #pragma unroll
                for (int t = 0; t < 4; ++t) qc[hf][t] = pack8(acc[t][0], acc[t][1]);
            }
            // ---- K projection, dh-halves ----
            #pragma unroll
            for (int hf = 0; hf < 2; ++hf) {
                const int RB = 32 + h * 4 + 2 * hf;
                f32x4 acc[4][2];
                #pragma unroll
                for (int t = 0; t < 4; ++t) { acc[t][0] = zf; acc[t][1] = zf; }
                #pragma unroll 4
                for (int ks = 0; ks < 16; ++ks) {
                    s16x8 w0 = wfragL<WB16>(wb, w, RB,     ks, lane);
                    s16x8 w1 = wfragL<WB16>(wb, w, RB + 1, ks, lane);
                    XF(ks)
                    acc[0][0]=MFB(af0,w0,acc[0][0]); acc[0][1]=MFB(af0,w1,acc[0][1]);
                    acc[1][0]=MFB(af1,w0,acc[1][0]); acc[1][1]=MFB(af1,w1,acc[1][1]);
                    acc[2][0]=MFB(af2,w0,acc[2][0]); acc[2][1]=MFB(af2,w1,acc[2][1]);
                    acc[3][0]=MFB(af3,w0,acc[3][0]); acc[3][1]=MFB(af3,w1,acc[3][1]);
                }
                #pragma unroll
                for (int t = 0; t < 4; ++t) kc[hf][t] = pack8(acc[t][0], acc[t][1]);
            }
            // ---- V projection as vT, dh-quarters (min register pressure) ----
            #pragma unroll
            for (int qv = 0; qv < 4; ++qv) {
                const int RB = 64 + h * 4 + qv;
                f32x4 acc0 = zf, acc1 = zf, acc2 = zf, acc3 = zf;
                #pragma unroll 4
                for (int ks = 0; ks < 16; ++ks) {
                    s16x8 w0 = wfragL<WB16>(wb, w, RB, ks, lane);
                    XF(ks)
                    acc0 = MFB(w0, af0, acc0); acc1 = MFB(w0, af1, acc1);
                    acc2 = MFB(w0, af2, acc2); acc3 = MFB(w0, af3, acc3);
                }
                vq[qv][0] = pack8(acc0, acc1);   // tok-tiles 0,1
                vq[qv][1] = pack8(acc2, acc3);   // tok-tiles 2,3
            }

            __syncthreads();             // X dead -> region = 8x8KiB wave slots

            // ---- q tile -> slot; read q A-frags ----
            #pragma unroll
            for (int hf = 0; hf < 2; ++hf)
                #pragma unroll
                for (int t = 0; t < 4; ++t)
                    #pragma unroll
                    for (int hc = 0; hc < 2; ++hc)
                        #pragma unroll
                        for (int rr = 0; rr < 4; ++rr) {
                            int row = t * 16 + g * 4 + rr;
                            int col = hf * 32 + hc * 16 + c;
                            *(short*)(slot + (row << 7) +
                                      ((col * 2) ^ ((row & 7) << 4))) =
                                qc[hf][t][hc * 4 + rr];
                        }
            s16x8 qf[8];
            #pragma unroll
            for (int ksl = 0; ksl < 2; ++ksl)
                #pragma unroll
                for (int tr = 0; tr < 4; ++tr)
                    qf[ksl * 4 + tr] =
                        *(const s16x8*)(slot + taddr(tr * 16 + c, ksl * 64 + g * 16));

            // ---- k tile -> slot (overwrites q); sim = q.k^T ----
            #pragma unroll
            for (int hf = 0; hf < 2; ++hf)
                #pragma unroll
                for (int t = 0; t < 4; ++t)
                    #pragma unroll
                    for (int hc = 0; hc < 2; ++hc)
                        #pragma unroll
                        for (int rr = 0; rr < 4; ++rr) {
                            int row = t * 16 + g * 4 + rr;
                            int col = hf * 32 + hc * 16 + c;
                            *(short*)(slot + (row << 7) +
                                      ((col * 2) ^ ((row & 7) << 4))) =
                                kc[hf][t][hc * 4 + rr];
                        }
            f32x4 sm[4][4];
            #pragma unroll
            for (int i = 0; i < 4; ++i)
                #pragma unroll
                for (int j = 0; j < 4; ++j) sm[i][j] = zf;
            #pragma unroll
            for (int ksl = 0; ksl < 2; ++ksl) {
                s16x8 kf0 = *(const s16x8*)(slot + taddr(c,      ksl * 64 + g * 16));
                s16x8 kf1 = *(const s16x8*)(slot + taddr(16 + c, ksl * 64 + g * 16));
                s16x8 kf2 = *(const s16x8*)(slot + taddr(32 + c, ksl * 64 + g * 16));
                s16x8 kf3 = *(const s16x8*)(slot + taddr(48 + c, ksl * 64 + g * 16));
                #pragma unroll
                for (int tr = 0; tr < 4; ++tr) {
                    sm[tr][0] = MFB(qf[ksl * 4 + tr], kf0, sm[tr][0]);
                    sm[tr][1] = MFB(qf[ksl * 4 + tr], kf1, sm[tr][1]);
                    sm[tr][2] = MFB(qf[ksl * 4 + tr], kf2, sm[tr][2]);
                    sm[tr][3] = MFB(qf[ksl * 4 + tr], kf3, sm[tr][3]);
                }
            }

            // ---- bias + softmax (in registers) ----
            const float* pbh = pb + h * 4096;
            #pragma unroll
            for (int tr = 0; tr < 4; ++tr) {
                #pragma unroll
                for (int rr = 0; rr < 4; ++rr) {
                    const int i = tr * 16 + g * 4 + rr;
                    float v0 = sm[tr][0][rr] + pbh[i * 64 +  0 + c];
                    float v1 = sm[tr][1][rr] + pbh[i * 64 + 16 + c];
                    float v2 = sm[tr][2][rr] + pbh[i * 64 + 32 + c];
                    float v3 = sm[tr][3][rr] + pbh[i * 64 + 48 + c];
                    float mx = fmaxf(fmaxf(v0, v1), fmaxf(v2, v3));
                    mx = fmaxf(mx, __shfl_xor(mx, 1));
                    mx = fmaxf(mx, __shfl_xor(mx, 2));
                    mx = fmaxf(mx, __shfl_xor(mx, 4));
                    mx = fmaxf(mx, __shfl_xor(mx, 8));
                    float p0 = __expf(v0 - mx);
                    float p1 = __expf(v1 - mx);
                    float p2 = __expf(v2 - mx);
                    float p3 = __expf(v3 - mx);
                    float ssum = p0 + p1 + p2 + p3;
                    ssum += __shfl_xor(ssum, 1);
                    ssum += __shfl_xor(ssum, 2);
                    ssum += __shfl_xor(ssum, 4);
                    ssum += __shfl_xor(ssum, 8);
                    float rinv = 1.0f / ssum;
                    sm[tr][0][rr] = p0 * rinv; sm[tr][1][rr] = p1 * rinv;
                    sm[tr][2][rr] = p2 * rinv; sm[tr][3][rr] = p3 * rinv;
                }
            }

            // ---- attn tile -> slot; read attn B-frags ----
            #pragma unroll
            for (int tr = 0; tr < 4; ++tr)
                #pragma unroll
                for (int tc = 0; tc < 4; ++tc)
                    #pragma unroll
                    for (int rr = 0; rr < 4; ++rr) {
                        int row = tr * 16 + g * 4 + rr;
                        int col = tc * 16 + c;
                        *(short*)(slot + (row << 7) +
                                  ((col * 2) ^ ((row & 7) << 4))) =
                            f2bf(sm[tr][tc][rr]);
                    }
            s16x8 baf[8];
            #pragma unroll
            for (int ksl = 0; ksl < 2; ++ksl)
                #pragma unroll
                for (int tt = 0; tt < 4; ++tt)
                    baf[ksl * 4 + tt] =
                        *(const s16x8*)(slot + taddr(tt * 16 + c, ksl * 64 + g * 16));

            // ---- vT tile -> slot (overwrites attn); PV: oT = vT . attn^T ----
            #pragma unroll
            for (int qv = 0; qv < 4; ++qv)
                #pragma unroll
                for (int tt = 0; tt < 4; ++tt)
                    #pragma unroll
                    for (int rr = 0; rr < 4; ++rr) {
                        int row = qv * 16 + g * 4 + rr;   // dh
                        int col = tt * 16 + c;            // tok
                        *(short*)(slot + (row << 7) +
                                  ((col * 2) ^ ((row & 7) << 4))) =
                            vq[qv][tt >> 1][(tt & 1) * 4 + rr];
                    }
            f32x4 oa[4][4];
            #pragma unroll
            for (int i = 0; i < 4; ++i)
                #pragma unroll
                for (int j = 0; j < 4; ++j) oa[i][j] = zf;
            #pragma unroll
            for (int ksl = 0; ksl < 2; ++ksl) {
                s16x8 a0 = *(const s16x8*)(slot + taddr(c,      ksl * 64 + g * 16));
                s16x8 a1 = *(const s16x8*)(slot + taddr(16 + c, ksl * 64 + g * 16));
                s16x8 a2 = *(const s16x8*)(slot + taddr(32 + c, ksl * 64 + g * 16));
                s16x8 a3 = *(const s16x8*)(slot + taddr(48 + c, ksl * 64 + g * 16));
                #pragma unroll
                for (int tt = 0; tt < 4; ++tt) {
                    oa[0][tt] = MFB(a0, baf[ksl * 4 + tt], oa[0][tt]);
                    oa[1][tt] = MFB(a1, baf[ksl * 4 + tt], oa[1][tt]);
                    oa[2][tt] = MFB(a2, baf[ksl * 4 + tt], oa[2][tt]);
                    oa[3][tt] = MFB(a3, baf[ksl * 4 + tt], oa[3][tt]);
                }
            }
            // oa[dht][tt] = out[tok=tt*16+c][dh=h*64+dht*16+g*4 ..+4): full-line nt
            #pragma unroll
            for (int dht = 0; dht < 4; ++dht)
                #pragma unroll
                for (int tt = 0; tt < 4; ++tt)
                    ntst4(outblk + (size_t)(tt * 16 + c) * DIM + h * 64 + dht * 16 + g * 4,
                          oa[dht][tt]);
        } else {
            // ---- focused: out = v = X . Wv^T (vT form), direct nt stores ----
            #pragma unroll
            for (int hf = 0; hf < 2; ++hf) {
                const int RB = 64 + h * 4 + 2 * hf;
                f32x4 va[2][4];
                #pragma unroll
                for (int i = 0; i < 2; ++i)
                    #pragma unroll
                    for (int j = 0; j < 4; ++j) va[i][j] = zf;
                #pragma unroll 4
                for (int ks = 0; ks < 16; ++ks) {
                    s16x8 w0 = wfragL<WB16>(wb, w, RB,     ks, lane);
                    s16x8 w1 = wfragL<WB16>(wb, w, RB + 1, ks, lane);
                    XF(ks)
                    va[0][0]=MFB(w0,af0,va[0][0]); va[0][1]=MFB(w0,af1,va[0][1]);
                    va[0][2]=MFB(w0,af2,va[0][2]); va[0][3]=MFB(w0,af3,va[0][3]);
                    va[1][0]=MFB(w1,af0,va[1][0]); va[1][1]=MFB(w1,af1,va[1][1]);
                    va[1][2]=MFB(w1,af2,va[1][2]); va[1][3]=MFB(w1,af3,va[1][3]);
                }
                #pragma unroll
                for (int dt = 0; dt < 2; ++dt)
                    #pragma unroll
                    for (int tt = 0; tt < 4; ++tt)
                        ntst4(outblk + (size_t)(tt * 16 + c) * DIM
                              + h * 64 + hf * 32 + dt * 16 + g * 4,
                              va[dt][tt]);
            }
        }
    }
}

extern "C" void kernel_launch(void* const* d_in, const int* in_sizes, int n_in,
                              void* d_out, int out_size, void* d_ws, size_t ws_size,
                              hipStream_t stream)
{
    const float* x  = (const float*)d_in[0];
    const float* w  = (const float*)d_in[1];
    const float* pb = (const float*)d_in[2];
    const unsigned int* mk = (const unsigned int*)d_in[3];
    float* out = (float*)d_out;

    const int LDS = 65536;
    const size_t wbytes = (size_t)1536 * 512 * sizeof(unsigned short);

    if (ws_size >= wbytes) {
        unsigned short* wbp = (unsigned short*)d_ws;
        conv_w<<<dim3(384), dim3(256), 0, stream>>>(w, wbp);
        hipFuncSetAttribute(reinterpret_cast<const void*>(&attn_all<1>),
                            hipFuncAttributeMaxDynamicSharedMemorySize, LDS);
        attn_all<1><<<dim3(GRIDB), dim3(512), LDS, stream>>>(x, w, wbp, pb, mk, out);
    } else {
        hipFuncSetAttribute(reinterpret_cast<const void*>(&attn_all<0>),
                            hipFuncAttributeMaxDynamicSharedMemorySize, LDS);
        attn_all<0><<<dim3(GRIDB), dim3(512), LDS, stream>>>(x, w, nullptr, pb, mk, out);
    }
}

// Round 9
// 294.690 us; speedup vs baseline: 5.8888x; 1.5427x over previous
//
#include <hip/hip_runtime.h>
#include <hip/hip_bf16.h>

// ---------------------------------------------------------------------------
// Round 9: merged single-dispatch kernel, R4's 16-wave high-occupancy shape
// with register pressure engineered under the 64-VGPR cap (split Q/K/V
// passes, packed bf16 intermediates, sequenced frag reads) => no scratch
// spill. Conflict-free X staging. One block per site; focused sites take the
// light v-projection path inside the same dispatch.
//   x:(2,1024,64,512) f32  w:(1536,512) f32  pb:(8,64,64) f32  mk:(2,) bool
// ---------------------------------------------------------------------------

typedef __attribute__((ext_vector_type(4))) float f32x4;
typedef __attribute__((ext_vector_type(8))) short s16x8;

#define DIM 512

__device__ __forceinline__ short f2bf(float f) {
    unsigned int u = __builtin_bit_cast(unsigned int, f);
    u += 0x7fffu + ((u >> 16) & 1u);
    return (short)(u >> 16);
}
__device__ __forceinline__ f32x4 ntld4(const float* p) {
    return __builtin_nontemporal_load((const f32x4*)p);
}
__device__ __forceinline__ void ntst4(float* p, f32x4 v) {
    __builtin_nontemporal_store(v, (f32x4*)p);
}
__device__ __forceinline__ s16x8 pack8(f32x4 a, f32x4 b) {
    s16x8 v;
    v[0] = f2bf(a[0]); v[1] = f2bf(a[1]); v[2] = f2bf(a[2]); v[3] = f2bf(a[3]);
    v[4] = f2bf(b[0]); v[5] = f2bf(b[1]); v[6] = f2bf(b[2]); v[7] = f2bf(b[3]);
    return v;
}
__device__ __forceinline__ int xaddr(int row, int kb) {   // 64x512 bf16, 1KiB rows
    return (row << 10) + (kb ^ ((row & 7) << 4));
}
__device__ __forceinline__ int taddr(int row, int kb) {   // 64x64 bf16, 128B rows
    return (row << 7) + (kb ^ ((row & 7) << 4));
}

// W pre-swizzle: frag chunk idx = (rowblk*16 + ks)*64 + lane -> one 1 KiB
// contiguous read per wave-fragment. q-scale (1/8) folded into Wq rows.
__global__ void conv_w(const float* __restrict__ w, unsigned short* __restrict__ wb) {
    int gid  = blockIdx.x * 256 + threadIdx.x;       // 0 .. 98303
    int lane = gid & 63;
    int ks   = (gid >> 6) & 15;
    int rowblk = gid >> 10;
    int row = rowblk * 16 + (lane & 15);
    int col = ks * 32 + (lane >> 4) * 8;
    const float* p = w + (size_t)row * DIM + col;
    f32x4 a = *(const f32x4*)p;
    f32x4 b = *(const f32x4*)(p + 4);
    float sc = (row < 512) ? 0.125f : 1.0f;
    a *= sc; b *= sc;
    *(s16x8*)(wb + (size_t)gid * 8) = pack8(a, b);
}

template<int WB16>
__device__ __forceinline__ s16x8 wfragL(const unsigned short* __restrict__ wb,
                                        const float* __restrict__ w,
                                        int rowblk, int ks, int lane) {
    if constexpr (WB16) {
        return *(const s16x8*)(wb + ((size_t)(rowblk * 16 + ks) * 64 + lane) * 8);
    } else {
        int row = rowblk * 16 + (lane & 15);
        int col = ks * 32 + (lane >> 4) * 8;
        const float* p = w + (size_t)row * DIM + col;
        f32x4 u0 = *(const f32x4*)p;
        f32x4 u1 = *(const f32x4*)(p + 4);
        float sc = (row < 512) ? 0.125f : 1.0f;
        u0 *= sc; u1 *= sc;
        return pack8(u0, u1);
    }
}

__device__ __forceinline__ bool decode_mask(const unsigned int* mk, int b) {
    unsigned int m0 = mk[0], m1 = mk[1];
    if (m0 <= 1u && m1 <= 1u) return ((b == 0) ? m0 : m1) != 0u;
    return ((const unsigned char*)mk)[b] != 0;
}

#define MFB(a, b, cc) __builtin_amdgcn_mfma_f32_16x16x32_bf16(a, b, cc, 0, 0, 0)

// X fragment reads (4 token-row tiles at K-slice ks) from region A (= smem)
#define XF(ks)                                                               \
    s16x8 af0 = *(const s16x8*)(smem + xaddr(c,      (ks) * 64 + g * 16));   \
    s16x8 af1 = *(const s16x8*)(smem + xaddr(16 + c, (ks) * 64 + g * 16));   \
    s16x8 af2 = *(const s16x8*)(smem + xaddr(32 + c, (ks) * 64 + g * 16));   \
    s16x8 af3 = *(const s16x8*)(smem + xaddr(48 + c, (ks) * 64 + g * 16));

template<int WB16>
__global__ __launch_bounds__(1024, 4)
void attn_merged(const float* __restrict__ x,
                 const float* __restrict__ w,
                 const unsigned short* __restrict__ wb,
                 const float* __restrict__ pb,
                 const unsigned int* __restrict__ mk,
                 float* __restrict__ out)
{
    extern __shared__ char smem[];
    const int tid  = threadIdx.x;
    const int lane = tid & 63;
    const int wave = tid >> 6;          // 0..15
    const int g    = lane >> 4;
    const int c    = lane & 15;
    const int hp   = wave >> 1;         // head
    const int hw2  = wave & 1;          // dh-half (proj) / token-half (attn)
    const int site = blockIdx.x;
    const bool focused = decode_mask(mk, site >> 10);
    const float* xblk   = x   + (size_t)site * (64 * DIM);
    float*       outblk = out + (size_t)site * (64 * DIM);
    const f32x4 zf = {0.f, 0.f, 0.f, 0.f};

    // ---- stage X: conflict-free (16-lane groups write 256B contiguous) ----
    {
        const int row = tid >> 4, c16 = tid & 15;
        const float* gp = xblk + row * DIM;
        #pragma unroll
        for (int j = 0; j < 4; ++j) {
            f32x4 a = ntld4(gp + j * 128 + c16 * 8);
            f32x4 b = ntld4(gp + j * 128 + c16 * 8 + 4);
            *(s16x8*)(smem + xaddr(row, j * 256 + c16 * 16)) = pack8(a, b);
        }
    }
    __syncthreads();                                         // (1) X ready

    if (focused) {
        // ---------- out = v = X . Wv^T (eye mask => attn = I) ----------
        const int RB = 64 + hp * 4 + 2 * hw2;
        f32x4 va[2][4];
        #pragma unroll
        for (int i = 0; i < 2; ++i)
            #pragma unroll
            for (int j = 0; j < 4; ++j) va[i][j] = zf;
        #pragma unroll 4
        for (int ks = 0; ks < 16; ++ks) {
            s16x8 wv0 = wfragL<WB16>(wb, w, RB,     ks, lane);
            s16x8 wv1 = wfragL<WB16>(wb, w, RB + 1, ks, lane);
            XF(ks)
            va[0][0]=MFB(wv0,af0,va[0][0]); va[0][1]=MFB(wv0,af1,va[0][1]);
            va[0][2]=MFB(wv0,af2,va[0][2]); va[0][3]=MFB(wv0,af3,va[0][3]);
            va[1][0]=MFB(wv1,af0,va[1][0]); va[1][1]=MFB(wv1,af1,va[1][1]);
            va[1][2]=MFB(wv1,af2,va[1][2]); va[1][3]=MFB(wv1,af3,va[1][3]);
        }
        // staged linear epilogue, two 32-row halves in region B
        char* stg = smem + 65536;
        #pragma unroll
        for (int h2 = 0; h2 < 2; ++h2) {
            #pragma unroll
            for (int sub = 0; sub < 2; ++sub)
                #pragma unroll
                for (int tn = 0; tn < 2; ++tn) {
                    int rl   = tn * 16 + c;                  // local token row
                    int colb = hp * 256 + hw2 * 128 + sub * 64 + g * 16;
                    *(f32x4*)(stg + rl * 2048 + (colb ^ ((rl & 7) << 4))) =
                        va[sub][h2 * 2 + tn];
                }
            __syncthreads();
            #pragma unroll
            for (int i = 0; i < 4; ++i) {
                int lin = i * 16384 + tid * 16;
                int rl = lin >> 11, off = lin & 2047;
                f32x4 v = *(const f32x4*)(stg + rl * 2048 + (off ^ ((rl & 7) << 4)));
                ntst4((float*)((char*)outblk + h2 * 65536 + lin), v);
            }
            if (h2 == 0) __syncthreads();
        }
        return;
    }

    // ===================== full-attention path =====================
    char* slotA = smem + hp * 8192;             // (X) -> k -> attn
    char* slotB = smem + 65536 + hp * 8192;     // q -> vT
    const int RQ = hp * 4 + 2 * hw2;
    const int RK = 32 + hp * 4 + 2 * hw2;

    // ---- Q pass (acc 32 regs) -> q tile straight to slotB ----
    {
        f32x4 acc[4][2];
        #pragma unroll
        for (int t = 0; t < 4; ++t) { acc[t][0] = zf; acc[t][1] = zf; }
        #pragma unroll 4
        for (int ks = 0; ks < 16; ++ks) {
            s16x8 w0 = wfragL<WB16>(wb, w, RQ,     ks, lane);
            s16x8 w1 = wfragL<WB16>(wb, w, RQ + 1, ks, lane);
            XF(ks)
            acc[0][0]=MFB(af0,w0,acc[0][0]); acc[0][1]=MFB(af0,w1,acc[0][1]);
            acc[1][0]=MFB(af1,w0,acc[1][0]); acc[1][1]=MFB(af1,w1,acc[1][1]);
            acc[2][0]=MFB(af2,w0,acc[2][0]); acc[2][1]=MFB(af2,w1,acc[2][1]);
            acc[3][0]=MFB(af3,w0,acc[3][0]); acc[3][1]=MFB(af3,w1,acc[3][1]);
        }
        #pragma unroll
        for (int t = 0; t < 4; ++t)
            #pragma unroll
            for (int hc = 0; hc < 2; ++hc)
                #pragma unroll
                for (int rr = 0; rr < 4; ++rr) {
                    int row = t * 16 + g * 4 + rr;
                    int col = hw2 * 32 + hc * 16 + c;
                    *(short*)(slotB + (row << 7) + ((col * 2) ^ ((row & 7) << 4))) =
                        f2bf(acc[t][hc][rr]);
                }
    }

    // ---- K pass (acc 32 regs) -> packed kc (16 regs) ----
    s16x8 kc[4];
    {
        f32x4 acc[4][2];
        #pragma unroll
        for (int t = 0; t < 4; ++t) { acc[t][0] = zf; acc[t][1] = zf; }
        #pragma unroll 4
        for (int ks = 0; ks < 16; ++ks) {
            s16x8 w0 = wfragL<WB16>(wb, w, RK,     ks, lane);
            s16x8 w1 = wfragL<WB16>(wb, w, RK + 1, ks, lane);
            XF(ks)
            acc[0][0]=MFB(af0,w0,acc[0][0]); acc[0][1]=MFB(af0,w1,acc[0][1]);
            acc[1][0]=MFB(af1,w0,acc[1][0]); acc[1][1]=MFB(af1,w1,acc[1][1]);
            acc[2][0]=MFB(af2,w0,acc[2][0]); acc[2][1]=MFB(af2,w1,acc[2][1]);
            acc[3][0]=MFB(af3,w0,acc[3][0]); acc[3][1]=MFB(af3,w1,acc[3][1]);
        }
        #pragma unroll
        for (int t = 0; t < 4; ++t) kc[t] = pack8(acc[t][0], acc[t][1]);
    }

    // ---- V pass as vT, two 1-rowblk sub-passes (acc 16 regs) ----
    s16x8 vc[4];
    #pragma unroll
    for (int sub = 0; sub < 2; ++sub) {
        const int RB = 64 + hp * 4 + 2 * hw2 + sub;
        f32x4 a0 = zf, a1 = zf, a2 = zf, a3 = zf;
        #pragma unroll 4
        for (int ks = 0; ks < 16; ++ks) {
            s16x8 wv = wfragL<WB16>(wb, w, RB, ks, lane);
            XF(ks)
            a0 = MFB(wv, af0, a0); a1 = MFB(wv, af1, a1);
            a2 = MFB(wv, af2, a2); a3 = MFB(wv, af3, a3);
        }
        vc[sub * 2]     = pack8(a0, a1);
        vc[sub * 2 + 1] = pack8(a2, a3);
    }

    __syncthreads();                                         // (2) X dead -> slots

    // ---- k -> slotA ----
    #pragma unroll
    for (int t = 0; t < 4; ++t)
        #pragma unroll
        for (int hc = 0; hc < 2; ++hc)
            #pragma unroll
            for (int rr = 0; rr < 4; ++rr) {
                int row = t * 16 + g * 4 + rr;
                int col = hw2 * 32 + hc * 16 + c;
                *(short*)(slotA + (row << 7) + ((col * 2) ^ ((row & 7) << 4))) =
                    kc[t][hc * 4 + rr];
            }
    __syncthreads();                                         // (3) q,k visible

    // ---- sim = q . k^T (token-split rows), frags sequenced (12 regs) ----
    f32x4 sm[2][4];
    #pragma unroll
    for (int i = 0; i < 2; ++i)
        #pragma unroll
        for (int j = 0; j < 4; ++j) sm[i][j] = zf;
    #pragma unroll
    for (int ks2 = 0; ks2 < 2; ++ks2) {
        s16x8 aq0 = *(const s16x8*)(slotB + taddr((2 * hw2 + 0) * 16 + c, ks2 * 64 + g * 16));
        s16x8 aq1 = *(const s16x8*)(slotB + taddr((2 * hw2 + 1) * 16 + c, ks2 * 64 + g * 16));
        #pragma unroll
        for (int j = 0; j < 4; ++j) {
            s16x8 bk = *(const s16x8*)(slotA + taddr(j * 16 + c, ks2 * 64 + g * 16));
            sm[0][j] = MFB(aq0, bk, sm[0][j]);
            sm[1][j] = MFB(aq1, bk, sm[1][j]);
        }
    }

    // ---- bias + softmax ----
    const float* pbh = pb + hp * 4096;
    #pragma unroll
    for (int tr = 0; tr < 2; ++tr) {
        #pragma unroll
        for (int rr = 0; rr < 4; ++rr) {
            const int i = 32 * hw2 + tr * 16 + g * 4 + rr;
            float v0 = sm[tr][0][rr] + pbh[i * 64 +  0 + c];
            float v1 = sm[tr][1][rr] + pbh[i * 64 + 16 + c];
            float v2 = sm[tr][2][rr] + pbh[i * 64 + 32 + c];
            float v3 = sm[tr][3][rr] + pbh[i * 64 + 48 + c];
            float mx = fmaxf(fmaxf(v0, v1), fmaxf(v2, v3));
            mx = fmaxf(mx, __shfl_xor(mx, 1));
            mx = fmaxf(mx, __shfl_xor(mx, 2));
            mx = fmaxf(mx, __shfl_xor(mx, 4));
            mx = fmaxf(mx, __shfl_xor(mx, 8));
            float p0 = __expf(v0 - mx);
            float p1 = __expf(v1 - mx);
            float p2 = __expf(v2 - mx);
            float p3 = __expf(v3 - mx);
            float ssum = p0 + p1 + p2 + p3;
            ssum += __shfl_xor(ssum, 1);
            ssum += __shfl_xor(ssum, 2);
            ssum += __shfl_xor(ssum, 4);
            ssum += __shfl_xor(ssum, 8);
            float rinv = 1.0f / ssum;
            sm[tr][0][rr] = p0 * rinv; sm[tr][1][rr] = p1 * rinv;
            sm[tr][2][rr] = p2 * rinv; sm[tr][3][rr] = p3 * rinv;
        }
    }
    __syncthreads();                                         // (4) q,k reads done

    // ---- attn -> slotA (own token-half rows) ----
    #pragma unroll
    for (int tr = 0; tr < 2; ++tr)
        #pragma unroll
        for (int tc = 0; tc < 4; ++tc)
            #pragma unroll
            for (int rr = 0; rr < 4; ++rr) {
                int row = 32 * hw2 + tr * 16 + g * 4 + rr;
                int col = tc * 16 + c;
                *(short*)(slotA + (row << 7) + ((col * 2) ^ ((row & 7) << 4))) =
                    f2bf(sm[tr][tc][rr]);
            }
    // ---- vT -> slotB (own dh-half rows) ----
    #pragma unroll
    for (int sub = 0; sub < 2; ++sub)
        #pragma unroll
        for (int t = 0; t < 4; ++t)
            #pragma unroll
            for (int rr = 0; rr < 4; ++rr) {
                int row = hw2 * 32 + sub * 16 + g * 4 + rr;
                int col = t * 16 + c;
                *(short*)(slotB + (row << 7) + ((col * 2) ^ ((row & 7) << 4))) =
                    vc[sub * 2 + (t >> 1)][(t & 1) * 4 + rr];
            }
    __syncthreads();                                         // (5) attn, vT visible

    // ---- PV: oT = vT . attn^T (token-split cols), frags sequenced ----
    f32x4 ot[4][2];
    #pragma unroll
    for (int i = 0; i < 4; ++i) { ot[i][0] = zf; ot[i][1] = zf; }
    #pragma unroll
    for (int ks2 = 0; ks2 < 2; ++ks2) {
        s16x8 ba0 = *(const s16x8*)(slotA + taddr((2 * hw2 + 0) * 16 + c, ks2 * 64 + g * 16));
        s16x8 ba1 = *(const s16x8*)(slotA + taddr((2 * hw2 + 1) * 16 + c, ks2 * 64 + g * 16));
        #pragma unroll
        for (int i = 0; i < 4; ++i) {
            s16x8 av = *(const s16x8*)(slotB + taddr(i * 16 + c, ks2 * 64 + g * 16));
            ot[i][0] = MFB(av, ba0, ot[i][0]);
            ot[i][1] = MFB(av, ba1, ot[i][1]);
        }
    }
    __syncthreads();                                         // (6) slots dead

    // ---- staged linear epilogue over full 128 KiB ----
    #pragma unroll
    for (int i = 0; i < 4; ++i)
        #pragma unroll
        for (int j = 0; j < 2; ++j) {
            int rl   = 32 * hw2 + j * 16 + c;                // token row
            int colb = hp * 256 + i * 64 + g * 16;           // dh byte offset
            *(f32x4*)(smem + rl * 2048 + (colb ^ ((rl & 7) << 4))) = ot[i][j];
        }
    __syncthreads();                                         // (7)
    #pragma unroll
    for (int i = 0; i < 8; ++i) {
        int lin = i * 16384 + tid * 16;
        int rl = lin >> 11, off = lin & 2047;
        f32x4 v = *(const f32x4*)(smem + rl * 2048 + (off ^ ((rl & 7) << 4)));
        ntst4((float*)((char*)outblk + lin), v);
    }
}

extern "C" void kernel_launch(void* const* d_in, const int* in_sizes, int n_in,
                              void* d_out, int out_size, void* d_ws, size_t ws_size,
                              hipStream_t stream)
{
    const float* x  = (const float*)d_in[0];
    const float* w  = (const float*)d_in[1];
    const float* pb = (const float*)d_in[2];
    const unsigned int* mk = (const unsigned int*)d_in[3];
    float* out = (float*)d_out;

    const int LDS = 131072;
    const size_t wbytes = (size_t)1536 * 512 * sizeof(unsigned short);

    if (ws_size >= wbytes) {
        unsigned short* wbp = (unsigned short*)d_ws;
        conv_w<<<dim3(384), dim3(256), 0, stream>>>(w, wbp);
        hipFuncSetAttribute(reinterpret_cast<const void*>(&attn_merged<1>),
                            hipFuncAttributeMaxDynamicSharedMemorySize, LDS);
        attn_merged<1><<<dim3(2048), dim3(1024), LDS, stream>>>(x, w, wbp, pb, mk, out);
    } else {
        hipFuncSetAttribute(reinterpret_cast<const void*>(&attn_merged<0>),
                            hipFuncAttributeMaxDynamicSharedMemorySize, LDS);
        attn_merged<0><<<dim3(2048), dim3(1024), LDS, stream>>>(x, w, nullptr, pb, mk, out);
    }
}